// Round 11
// baseline (111.858 us; speedup 1.0000x reference)
//
#include <hip/hip_runtime.h>
#include <hip/hip_bf16.h>

typedef _Float16 f16;
typedef __attribute__((ext_vector_type(2))) __fp16 h16x2;   // cvt_pkrtz return type
typedef __attribute__((ext_vector_type(4))) _Float16 f16x4;
typedef __attribute__((ext_vector_type(8))) _Float16 f16x8;
typedef __attribute__((ext_vector_type(4))) float f32x4;
typedef __attribute__((ext_vector_type(16))) float f32x16;
typedef __attribute__((ext_vector_type(4))) unsigned int u32x4;

#define CD 256
#define ND 4096
#define GD 32
#define KVB 32          // keys per iteration

// async global->LDS, 16B per lane, lds dest must be wave-uniform base
__device__ __forceinline__ void gl_lds16(const f16* g, f16* l) {
    __builtin_amdgcn_global_load_lds(
        (const __attribute__((address_space(1))) unsigned int*)g,
        (__attribute__((address_space(3))) unsigned int*)l,
        16, 0, 0);
}

// ============================================================================
// Kernel 1: fused QKV projection.  p[b,o,n] = sum_c W[o,c] x[b,c,n] + bias[o]
// Q,K written TRANSPOSED [b][n][c] f16; V natural [b][c][n] f16.
// ============================================================================
__global__ __launch_bounds__(256)
void k_proj_qkv(const float* __restrict__ x,
                const float* __restrict__ Wq, const float* __restrict__ bq,
                const float* __restrict__ Wk, const float* __restrict__ bk,
                const float* __restrict__ Wv, const float* __restrict__ bv,
                f16* __restrict__ Qt, f16* __restrict__ Kt, f16* __restrict__ Vb)
{
    __shared__ f16 As[3][64][40];
    __shared__ f16 Bs[64][40];
    __shared__ f16 Ts[64][72];

    const int t  = threadIdx.x;
    const int n0 = blockIdx.x * 64;
    const int o0 = blockIdx.y * 64;
    const int bb = blockIdx.z;

    const float* Ws[3] = { Wq, Wk, Wv };
    const float* bs[3] = { bq, bk, bv };

    const int w  = t >> 6;
    const int l  = t & 63;
    const int lr = l & 15;
    const int lg = l >> 4;
    const int wo = (w >> 1) * 32;
    const int wn = (w & 1) * 32;

    const int sl = t & 63;
    const int k8 = (t >> 6) * 8;

    f32x4 acc[3][2][2] = {};

    for (int ck = 0; ck < CD; ck += 32) {
        __syncthreads();
#pragma unroll
        for (int p = 0; p < 3; ++p) {
            const float* s = Ws[p] + (size_t)(o0 + sl) * CD + ck + k8;
            f16x8 v;
#pragma unroll
            for (int u = 0; u < 8; ++u) v[u] = (f16)s[u];
            *(f16x8*)&As[p][sl][k8] = v;
        }
        {
            const float* s = x + ((size_t)bb * CD + ck + k8) * ND + n0 + sl;
            f16x8 v;
#pragma unroll
            for (int u = 0; u < 8; ++u) v[u] = (f16)s[(size_t)u * ND];
            *(f16x8*)&Bs[sl][k8] = v;
        }
        __syncthreads();
        f16x8 b0 = *(const f16x8*)&Bs[wn + lr][lg * 8];
        f16x8 b1 = *(const f16x8*)&Bs[wn + 16 + lr][lg * 8];
#pragma unroll
        for (int p = 0; p < 3; ++p) {
            f16x8 a0 = *(const f16x8*)&As[p][wo + lr][lg * 8];
            f16x8 a1 = *(const f16x8*)&As[p][wo + 16 + lr][lg * 8];
            acc[p][0][0] = __builtin_amdgcn_mfma_f32_16x16x32_f16(a0, b0, acc[p][0][0], 0, 0, 0);
            acc[p][0][1] = __builtin_amdgcn_mfma_f32_16x16x32_f16(a0, b1, acc[p][0][1], 0, 0, 0);
            acc[p][1][0] = __builtin_amdgcn_mfma_f32_16x16x32_f16(a1, b0, acc[p][1][0], 0, 0, 0);
            acc[p][1][1] = __builtin_amdgcn_mfma_f32_16x16x32_f16(a1, b1, acc[p][1][1], 0, 0, 0);
        }
    }

    // Q, K: transpose via Ts then coalesced [n][c] writes
#pragma unroll
    for (int p = 0; p < 2; ++p) {
        __syncthreads();
#pragma unroll
        for (int so = 0; so < 2; ++so)
#pragma unroll
            for (int r = 0; r < 4; ++r) {
                int orow  = wo + so * 16 + lg * 4 + r;
                float bv_ = bs[p][o0 + orow];
#pragma unroll
                for (int sn = 0; sn < 2; ++sn)
                    Ts[orow][wn + sn * 16 + lr] = (f16)(acc[p][so][sn][r] + bv_);
            }
        __syncthreads();
        f16* dst = (p == 0) ? Qt : Kt;
        int n  = t >> 2;
        int o8 = (t & 3) * 16;
        f16 tmp[16];
#pragma unroll
        for (int u = 0; u < 16; ++u) tmp[u] = Ts[o8 + u][n];
        f16* g = dst + ((size_t)bb * ND + n0 + n) * CD + o0 + o8;
        *(f16x8*)g       = *(f16x8*)&tmp[0];
        *(f16x8*)(g + 8) = *(f16x8*)&tmp[8];
    }
    // V: direct [c][n] writes
#pragma unroll
    for (int so = 0; so < 2; ++so)
#pragma unroll
        for (int r = 0; r < 4; ++r) {
            int orow  = wo + so * 16 + lg * 4 + r;
            float bv_ = bv[o0 + orow];
#pragma unroll
            for (int sn = 0; sn < 2; ++sn) {
                int ncol = wn + sn * 16 + lr;
                Vb[((size_t)bb * CD + o0 + orow) * ND + n0 + ncol] =
                    (f16)(acc[2][so][sn][r] + bv_);
            }
        }
}

// ============================================================================
// Kernel 2: flash attention, split-K (template KSN), 32x32x16 MFMA version.
// 4 waves x 32 queries (QBLK=128).  KVB=32 keys/iter, double-buffered LDS,
// 2 blocks/CU.  SWAPPED QK^T as ONE 32x32 tile/wave: lane holds 16 of 32 m
// for q=lane&31 -> softmax = 1 shfl(max) + 1 shfl(sum).  P->PV operand built
// fully in-register via cvt_pkrtz + shfl_xor(32) (no P LDS buffer).
// D-layout (m101): col=lane&31, row=(reg&3)+8*(reg>>2)+4*(lane>>5).
// ============================================================================
template<int KSN>
__global__ __launch_bounds__(256, 2)
void k_attn(const f16* __restrict__ Qt, const f16* __restrict__ Kt,
            const f16* __restrict__ Vb, f16* __restrict__ Op,
            float* __restrict__ ml)
{
    __shared__ f16 Ks[2][32 * 256];   // [buf][row][chunk16B ^ (row&7)]  2x16 KB
    __shared__ f16 Vs[2][256 * 32];   // [buf][c][chunk16B ^ ((c>>1)&3)] 2x16 KB

    const int t   = threadIdx.x;
    const int w   = t >> 6;          // 0..3
    const int l   = t & 63;
    const int q32 = l & 31;          // this lane's query column
    const int hi  = l >> 5;          // 0/1 half

    // ---- XCD-pinned decode ----
    const int bid = blockIdx.x;
    int bb, ks, qi;
    if constexpr (KSN == 8) {
        int xcd = bid & 7;
        bb = xcd & 1;
        ks = (xcd >> 1) | ((bid >> 8) << 2);
        qi = (bid >> 3) & 31;
    } else {   // KSN == 4
        bb = bid & 1;
        ks = (bid >> 1) & 3;
        qi = bid >> 3;
    }
    const int q0 = qi * 128 + w * 32;

    // Q fragments: 16 MFMA-k-steps, B operand col=q32, k=(hi)*8+e
    f16x8 qf[16];
#pragma unroll
    for (int n = 0; n < 16; ++n)
        qf[n] = *(const f16x8*)(Qt + ((size_t)bb * ND + q0 + q32) * CD + n * 16 + hi * 8);

    f32x16 oacc[8] = {};      // 8 c-chunks of 32 rows; col=q32
    float row_m = -3.0e38f, row_l = 0.f;

    const int kv0 = ks * (ND / KSN);
    const f16* ktb = Kt + (size_t)bb * ND * CD;
    const f16* vbb = Vb + (size_t)bb * CD * ND;

    // per-lane loop-invariant staging offsets (elements) — identical to r9
    int koff[4], voff[4];
#pragma unroll
    for (int j = 0; j < 4; ++j) {
        int v   = (w * 4 + j) * 64 + l;
        int row = v >> 5;
        int ch  = (v & 31) ^ (row & 7);
        koff[j] = row * CD + ch * 8;
        int c   = v >> 2;
        int u   = (v & 3) ^ ((c >> 1) & 3);
        voff[j] = c * ND + u * 8;
    }

    auto stage = [&](int m0, int bi) {
#pragma unroll
        for (int j = 0; j < 4; ++j)
            gl_lds16(ktb + (size_t)m0 * CD + koff[j], &Ks[bi][(w * 4 + j) * 512]);
#pragma unroll
        for (int j = 0; j < 4; ++j)
            gl_lds16(vbb + m0 + voff[j], &Vs[bi][(w * 4 + j) * 512]);
    };

    stage(kv0, 0);
    __syncthreads();    // drains vmcnt; tile 0 resident

    const int NIT = (ND / KSN) / KVB;
    for (int it = 0; it < NIT; ++it) {
        const int bi = it & 1;
        if (it + 1 < NIT) stage(kv0 + (it + 1) * KVB, bi ^ 1);

        // ---- QK^T: S[32 m][32 q] as one 32x32 tile, two K-chains of 8 ----
        f32x16 sa = {}, sb = {};
        __builtin_amdgcn_s_setprio(1);
#pragma unroll
        for (int n = 0; n < 16; n += 2) {
            // A=K fragment: row m = q32, k-chunk index (2n+hi) / (2n+2+hi)
            f16x8 ka = *(const f16x8*)&Ks[bi][q32 * 256 + (((2 * n + hi) ^ (q32 & 7))) * 8];
            f16x8 kb = *(const f16x8*)&Ks[bi][q32 * 256 + (((2 * n + 2 + hi) ^ (q32 & 7))) * 8];
            sa = __builtin_amdgcn_mfma_f32_32x32x16_f16(ka, qf[n],     sa, 0, 0, 0);
            sb = __builtin_amdgcn_mfma_f32_32x32x16_f16(kb, qf[n + 1], sb, 0, 0, 0);
        }
        __builtin_amdgcn_s_setprio(0);

        // ---- merge + lane-local online softmax (defer-max THR=5) ----
        float s[16];
#pragma unroll
        for (int r = 0; r < 16; ++r) s[r] = sa[r] + sb[r];

        float pm = s[0];
#pragma unroll
        for (int r = 1; r < 16; ++r) pm = fmaxf(pm, s[r]);
        pm = fmaxf(pm, __shfl_xor(pm, 32));
        bool need = (pm > row_m + 5.0f);
        float nm  = need ? pm : row_m;
        float p[16];
#pragma unroll
        for (int r = 0; r < 16; ++r) p[r] = __expf(s[r] - nm);
        float ps = 0.f;
#pragma unroll
        for (int r = 0; r < 16; ++r) ps += p[r];
        ps += __shfl_xor(ps, 32);
        if (__any(need)) {
            float sc = __expf(row_m - nm);   // == 1 for lanes w/o change
            row_l = row_l * sc + ps;
#pragma unroll
            for (int cc = 0; cc < 8; ++cc)
#pragma unroll
                for (int r = 0; r < 16; ++r) oacc[cc][r] *= sc;
        } else {
            row_l += ps;
        }
        row_m = nm;

        // ---- P -> PV B-operand, fully in-register ----
        // lane (q,hi) reg r holds P[m=(r&3)+8*(r>>2)+4*hi][q]; pack pairs:
        unsigned int wv[8], ov[8];
#pragma unroll
        for (int c = 0; c < 4; ++c) {
            h16x2 a = __builtin_amdgcn_cvt_pkrtz(p[4 * c],     p[4 * c + 1]);
            h16x2 b = __builtin_amdgcn_cvt_pkrtz(p[4 * c + 2], p[4 * c + 3]);
            wv[2 * c]     = __builtin_bit_cast(unsigned int, a);
            wv[2 * c + 1] = __builtin_bit_cast(unsigned int, b);
        }
#pragma unroll
        for (int i = 0; i < 8; ++i) ov[i] = __shfl_xor(wv[i], 32);
        // B_j (j=0: m 0..15, j=1: m 16..31), lane needs m = 16j+8hi .. +7:
        //   hi=0: {own.w[2j], other.w[2j]}   hi=1: {other.w[2j+1], own.w[2j+1]}
        f16x8 pb[2];
#pragma unroll
        for (int j = 0; j < 2; ++j) {
            u32x4 bwords;
            bwords[0] = hi ? ov[4 * j + 2] : wv[4 * j];
            bwords[1] = hi ? ov[4 * j + 3] : wv[4 * j + 1];
            bwords[2] = hi ? wv[4 * j + 2] : ov[4 * j];
            bwords[3] = hi ? wv[4 * j + 3] : ov[4 * j + 1];
            pb[j] = __builtin_bit_cast(f16x8, bwords);
        }

        // ---- PV: O[c][q] += V[c][m] * P[m][q], 8 c-chunks x 2 m-halves ----
        __builtin_amdgcn_s_setprio(1);
#pragma unroll
        for (int cc = 0; cc < 8; ++cc) {
            int crow = cc * 32 + q32;
            int sw   = (crow >> 1) & 3;
            f16x8 v0 = *(const f16x8*)&Vs[bi][crow * 32 + ((hi       ^ sw)) * 8];
            f16x8 v1 = *(const f16x8*)&Vs[bi][crow * 32 + (((2 + hi) ^ sw)) * 8];
            oacc[cc] = __builtin_amdgcn_mfma_f32_32x32x16_f16(v0, pb[0], oacc[cc], 0, 0, 0);
            oacc[cc] = __builtin_amdgcn_mfma_f32_32x32x16_f16(v1, pb[1], oacc[cc], 0, 0, 0);
        }
        __builtin_amdgcn_s_setprio(0);
        __syncthreads();   // drains stage(it+1); frees buffers for next iter
    }

    // ---- write unnormalized partial + (m,l) ----
#pragma unroll
    for (int cc = 0; cc < 8; ++cc)
#pragma unroll
        for (int r = 0; r < 16; ++r) {
            int cch = cc * 32 + (r & 3) + 8 * (r >> 2) + 4 * hi;
            Op[(((size_t)ks * 2 + bb) * CD + cch) * ND + q0 + q32] = (f16)oacc[cc][r];
        }
    if (l < 32) {
        int n = q0 + l;
        ml[((ks * 2 + bb) * 2 + 0) * ND + n] = row_m;
        ml[((ks * 2 + bb) * 2 + 1) * ND + n] = row_l;
    }
}

// ============================================================================
// Kernel 2b-i: per-n combine weights  wq[ks][b][n] = exp(m-M)/L
// ============================================================================
template<int KSN>
__global__ __launch_bounds__(256)
void k_ml(const float* __restrict__ ml, float* __restrict__ wq)
{
    int i = blockIdx.x * 256 + threadIdx.x;   // i over B*ND
    int b = i / ND, n = i % ND;
    float m[KSN], lv[KSN];
#pragma unroll
    for (int ks = 0; ks < KSN; ++ks) {
        m[ks]  = ml[((ks * 2 + b) * 2 + 0) * ND + n];
        lv[ks] = ml[((ks * 2 + b) * 2 + 1) * ND + n];
    }
    float M = m[0];
#pragma unroll
    for (int ks = 1; ks < KSN; ++ks) M = fmaxf(M, m[ks]);
    float wgt[KSN], L = 0.f;
#pragma unroll
    for (int ks = 0; ks < KSN; ++ks) { wgt[ks] = __expf(m[ks] - M); L += wgt[ks] * lv[ks]; }
    float inv = 1.0f / L;
#pragma unroll
    for (int ks = 0; ks < KSN; ++ks)
        wq[(ks * 2 + b) * ND + n] = wgt[ks] * inv;
}

// ============================================================================
// Kernel 2b-ii: combine split-K partials -> Hb[b][c][n] f16 (vectorized)
// ============================================================================
template<int KSN>
__global__ __launch_bounds__(256)
void k_comb(const f16* __restrict__ Op, const float* __restrict__ wq,
            f16* __restrict__ Hb)
{
    size_t i = (size_t)blockIdx.x * 256 + threadIdx.x;   // one f16x8 each
    int n0 = (int)(i % (ND / 8)) * 8;
    int c  = (int)((i / (ND / 8)) % CD);
    int b  = (int)(i / ((size_t)CD * (ND / 8)));

    float acc[8] = {};
#pragma unroll
    for (int ks = 0; ks < KSN; ++ks) {
        f16x8 o = *(const f16x8*)(Op + (((size_t)ks * 2 + b) * CD + c) * ND + n0);
        const float* wp = wq + (ks * 2 + b) * ND + n0;
        float4 w0 = *(const float4*)wp;
        float4 w1 = *(const float4*)(wp + 4);
        acc[0] += w0.x * (float)o[0]; acc[1] += w0.y * (float)o[1];
        acc[2] += w0.z * (float)o[2]; acc[3] += w0.w * (float)o[3];
        acc[4] += w1.x * (float)o[4]; acc[5] += w1.y * (float)o[5];
        acc[6] += w1.z * (float)o[6]; acc[7] += w1.w * (float)o[7];
    }
    f16x8 h;
#pragma unroll
    for (int u = 0; u < 8; ++u) h[u] = (f16)acc[u];
    *(f16x8*)(Hb + ((size_t)b * CD + c) * ND + n0) = h;
}

// ============================================================================
// Kernel 3: output projection + residual.  Yh = f16(Wo@H + bo + x)
// Emits deterministic per-block GroupNorm partials (f32, pre-rounding).
// ============================================================================
__global__ __launch_bounds__(256)
void k_proj_o(const f16* __restrict__ Hb, const float* __restrict__ Wo,
              const float* __restrict__ bo, const float* __restrict__ x,
              f16* __restrict__ Yh, float* __restrict__ part)
{
    __shared__ f16 As[64][40];
    __shared__ f16 Bs[64][40];
    __shared__ float rs[4][2][2][2];   // [wave][so][lg>>1][{s,s2}]

    const int t  = threadIdx.x;
    const int n0 = blockIdx.x * 64;
    const int o0 = blockIdx.y * 64;
    const int bb = blockIdx.z;

    const int w  = t >> 6;
    const int l  = t & 63;
    const int lr = l & 15;
    const int lg = l >> 4;
    const int wo = (w >> 1) * 32;
    const int wn = (w & 1) * 32;

    const int sl = t & 63;
    const int k8 = (t >> 6) * 8;

    f32x4 acc[2][2] = {};

    for (int ck = 0; ck < CD; ck += 32) {
        __syncthreads();
        {
            const float* s = Wo + (size_t)(o0 + sl) * CD + ck + k8;
            f16x8 v;
#pragma unroll
            for (int u = 0; u < 8; ++u) v[u] = (f16)s[u];
            *(f16x8*)&As[sl][k8] = v;
        }
        {
            const f16* s = Hb + ((size_t)bb * CD + ck + k8) * ND + n0 + sl;
            f16x8 v;
#pragma unroll
            for (int u = 0; u < 8; ++u) v[u] = s[(size_t)u * ND];
            *(f16x8*)&Bs[sl][k8] = v;
        }
        __syncthreads();
        f16x8 a0 = *(const f16x8*)&As[wo + lr][lg * 8];
        f16x8 a1 = *(const f16x8*)&As[wo + 16 + lr][lg * 8];
        f16x8 b0 = *(const f16x8*)&Bs[wn + lr][lg * 8];
        f16x8 b1 = *(const f16x8*)&Bs[wn + 16 + lr][lg * 8];
        acc[0][0] = __builtin_amdgcn_mfma_f32_16x16x32_f16(a0, b0, acc[0][0], 0, 0, 0);
        acc[0][1] = __builtin_amdgcn_mfma_f32_16x16x32_f16(a0, b1, acc[0][1], 0, 0, 0);
        acc[1][0] = __builtin_amdgcn_mfma_f32_16x16x32_f16(a1, b0, acc[1][0], 0, 0, 0);
        acc[1][1] = __builtin_amdgcn_mfma_f32_16x16x32_f16(a1, b1, acc[1][1], 0, 0, 0);
    }

#pragma unroll
    for (int so = 0; so < 2; ++so) {
        float ls = 0.f, ls2 = 0.f;
#pragma unroll
        for (int r = 0; r < 4; ++r) {
            int orow  = wo + so * 16 + lg * 4 + r;
            float bv_ = bo[o0 + orow];
#pragma unroll
            for (int sn = 0; sn < 2; ++sn) {
                int ncol   = wn + sn * 16 + lr;
                size_t idx = ((size_t)bb * CD + o0 + orow) * ND + n0 + ncol;
                float v = acc[so][sn][r] + bv_ + x[idx];
                Yh[idx] = (f16)v;
                ls  += v;
                ls2 += v * v;
            }
        }
        // deterministic reduce over lanes sharing the same group
#pragma unroll
        for (int m = 1; m <= 16; m <<= 1) {
            ls  += __shfl_xor(ls, m);
            ls2 += __shfl_xor(ls2, m);
        }
        if ((l & 31) == 0) {
            rs[w][so][l >> 5][0] = ls;
            rs[w][so][l >> 5][1] = ls2;
        }
    }
    __syncthreads();
    if (t < 16) {
        int gl = t >> 1, st = t & 1;
        int a = gl >> 2, so = (gl >> 1) & 1, lh = gl & 1;
        float v = rs[2 * a][so][lh][st] + rs[2 * a + 1][so][lh][st];
        part[(((size_t)bb * GD + (o0 >> 3) + gl) * 64 + blockIdx.x) * 2 + st] = v;
    }
}

// ============================================================================
// Kernel 4: GroupNorm (from partials) + SiLU, single pass, f16 in / f32 out
// ============================================================================
__global__ __launch_bounds__(256)
void k_gn_silu(const f16* __restrict__ Yh, const float* __restrict__ part,
               const float* __restrict__ gamma, const float* __restrict__ beta,
               float* __restrict__ out)
{
    const int g  = blockIdx.x, b = blockIdx.y, nq = blockIdx.z;
    const int t  = threadIdx.x;

    __shared__ float mr[2];
    if (t < 64) {
        float s  = part[(((size_t)b * GD + g) * 64 + t) * 2 + 0];
        float s2 = part[(((size_t)b * GD + g) * 64 + t) * 2 + 1];
#pragma unroll
        for (int m = 1; m < 64; m <<= 1) {
            s  += __shfl_xor(s, m);
            s2 += __shfl_xor(s2, m);
        }
        if (t == 0) {
            float mean = s / 32768.f;
            float var  = s2 / 32768.f - mean * mean;
            mr[0] = mean;
            mr[1] = rsqrtf(var + 1e-5f);
        }
    }
    __syncthreads();
    const float mean = mr[0], rstd = mr[1];

    const size_t base = ((size_t)b * CD + g * 8) * ND;
    const f16x8* src = (const f16x8*)(Yh + base);

    for (int i = t; i < 1024; i += 256) {
        int ch = i >> 7;
        int nn = i & 127;
        f16x8 v = src[ch * (ND / 8) + nq * 128 + nn];
        int c = g * 8 + ch;
        float ga = gamma[c], be = beta[c];
        float ob[8];
#pragma unroll
        for (int u = 0; u < 8; ++u) {
            float yn = ((float)v[u] - mean) * rstd * ga + be;
            float sg = 1.0f / (1.0f + __expf(-yn));
            ob[u] = yn * sg;
        }
        float* dp = out + base + (size_t)ch * ND + nq * 1024 + nn * 8;
        *(float4*)dp       = *(float4*)&ob[0];
        *(float4*)(dp + 4) = *(float4*)&ob[4];
    }
}

// ============================================================================
extern "C" void kernel_launch(void* const* d_in, const int* in_sizes, int n_in,
                              void* d_out, int out_size, void* d_ws, size_t ws_size,
                              hipStream_t stream)
{
    const float* x     = (const float*)d_in[0];
    const float* Wq    = (const float*)d_in[1];
    const float* bq    = (const float*)d_in[2];
    const float* Wk    = (const float*)d_in[3];
    const float* bk    = (const float*)d_in[4];
    const float* Wv    = (const float*)d_in[5];
    const float* bv    = (const float*)d_in[6];
    const float* Wo    = (const float*)d_in[7];
    const float* bo    = (const float*)d_in[8];
    const float* gamma = (const float*)d_in[9];
    const float* beta  = (const float*)d_in[10];

    char* ws = (char*)d_ws;
    f16* Qt = (f16*)(ws);                    //  0..4 MiB   [B][N][C]
    f16* Kt = (f16*)(ws + (4u << 20));       //  4..8 MiB   [B][N][C]
    f16* Vb = (f16*)(ws + (8u << 20));       //  8..12 MiB  [B][C][N]
    f16* Hb = (f16*)(ws + (12u << 20));      // 12..16 MiB  [B][C][N]
    f16* Op = (f16*)(ws + (16u << 20));      // 16.. MiB    [KSN][B][C][N]
    f16* Yh = (f16*)(ws + (16u << 20));      // reuses Op region after combine

    const bool big = ws_size >= (50ull << 20);

    k_proj_qkv<<<dim3(64, 4, 2), 256, 0, stream>>>(x, Wq, bq, Wk, bk, Wv, bv, Qt, Kt, Vb);

    if (big) {
        constexpr int KSN = 8;
        float* ml   = (float*)(ws + (48u << 20));                 // 512 KB
        float* wq   = (float*)(ws + (48u << 20) + (768u << 10));  // 256 KB
        float* part = (float*)(ws + (49u << 20) + (512u << 10));  // 32 KB
        k_attn<KSN><<<dim3(32 * KSN * 2), 256, 0, stream>>>(Qt, Kt, Vb, Op, ml);
        k_ml<KSN><<<dim3((2 * ND) / 256), 256, 0, stream>>>(ml, wq);
        k_comb<KSN><<<dim3((2 * CD * ND / 8) / 256), 256, 0, stream>>>(Op, wq, Hb);
        k_proj_o<<<dim3(64, 4, 2), 256, 0, stream>>>(Hb, Wo, bo, x, Yh, part);
        k_gn_silu<<<dim3(GD, 2, 4), 256, 0, stream>>>(Yh, part, gamma, beta, (float*)d_out);
    } else {
        constexpr int KSN = 4;
        float* ml   = (float*)(ws + (32u << 20));                 // 256 KB
        float* wq   = (float*)(ws + (32u << 20) + (512u << 10));  // 128 KB
        float* part = (float*)(ws + (33u << 20));                 // 32 KB
        k_attn<KSN><<<dim3(32 * KSN * 2), 256, 0, stream>>>(Qt, Kt, Vb, Op, ml);
        k_ml<KSN><<<dim3((2 * ND) / 256), 256, 0, stream>>>(ml, wq);
        k_comb<KSN><<<dim3((2 * CD * ND / 8) / 256), 256, 0, stream>>>(Op, wq, Hb);
        k_proj_o<<<dim3(64, 4, 2), 256, 0, stream>>>(Hb, Wo, bo, x, Yh, part);
        k_gn_silu<<<dim3(GD, 2, 4), 256, 0, stream>>>(Yh, part, gamma, beta, (float*)d_out);
    }
}

// Round 13
// 104.310 us; speedup vs baseline: 1.0724x; 1.0724x over previous
//
#include <hip/hip_runtime.h>
#include <hip/hip_bf16.h>

typedef _Float16 f16;
typedef __attribute__((ext_vector_type(2))) __fp16 h16x2;   // cvt_pkrtz return type
typedef __attribute__((ext_vector_type(4))) _Float16 f16x4;
typedef __attribute__((ext_vector_type(8))) _Float16 f16x8;
typedef __attribute__((ext_vector_type(4))) float f32x4;
typedef __attribute__((ext_vector_type(16))) float f32x16;
typedef __attribute__((ext_vector_type(4))) unsigned int u32x4;

#define CD 256
#define ND 4096
#define GD 32
#define KVB 32          // keys per iteration

// async global->LDS, 16B per lane, lds dest must be wave-uniform base
__device__ __forceinline__ void gl_lds16(const f16* g, f16* l) {
    __builtin_amdgcn_global_load_lds(
        (const __attribute__((address_space(1))) unsigned int*)g,
        (__attribute__((address_space(3))) unsigned int*)l,
        16, 0, 0);
}

// ============================================================================
// Kernel 1: fused QKV projection.  p[b,o,n] = sum_c W[o,c] x[b,c,n] + bias[o]
// Q,K written TRANSPOSED [b][n][c] f16; V natural [b][c][n] f16.
// ============================================================================
__global__ __launch_bounds__(256)
void k_proj_qkv(const float* __restrict__ x,
                const float* __restrict__ Wq, const float* __restrict__ bq,
                const float* __restrict__ Wk, const float* __restrict__ bk,
                const float* __restrict__ Wv, const float* __restrict__ bv,
                f16* __restrict__ Qt, f16* __restrict__ Kt, f16* __restrict__ Vb)
{
    __shared__ f16 As[3][64][40];
    __shared__ f16 Bs[64][40];
    __shared__ f16 Ts[64][72];

    const int t  = threadIdx.x;
    const int n0 = blockIdx.x * 64;
    const int o0 = blockIdx.y * 64;
    const int bb = blockIdx.z;

    const float* Ws[3] = { Wq, Wk, Wv };
    const float* bs[3] = { bq, bk, bv };

    const int w  = t >> 6;
    const int l  = t & 63;
    const int lr = l & 15;
    const int lg = l >> 4;
    const int wo = (w >> 1) * 32;
    const int wn = (w & 1) * 32;

    const int sl = t & 63;
    const int k8 = (t >> 6) * 8;

    f32x4 acc[3][2][2] = {};

    for (int ck = 0; ck < CD; ck += 32) {
        __syncthreads();
#pragma unroll
        for (int p = 0; p < 3; ++p) {
            const float* s = Ws[p] + (size_t)(o0 + sl) * CD + ck + k8;
            f16x8 v;
#pragma unroll
            for (int u = 0; u < 8; ++u) v[u] = (f16)s[u];
            *(f16x8*)&As[p][sl][k8] = v;
        }
        {
            const float* s = x + ((size_t)bb * CD + ck + k8) * ND + n0 + sl;
            f16x8 v;
#pragma unroll
            for (int u = 0; u < 8; ++u) v[u] = (f16)s[(size_t)u * ND];
            *(f16x8*)&Bs[sl][k8] = v;
        }
        __syncthreads();
        f16x8 b0 = *(const f16x8*)&Bs[wn + lr][lg * 8];
        f16x8 b1 = *(const f16x8*)&Bs[wn + 16 + lr][lg * 8];
#pragma unroll
        for (int p = 0; p < 3; ++p) {
            f16x8 a0 = *(const f16x8*)&As[p][wo + lr][lg * 8];
            f16x8 a1 = *(const f16x8*)&As[p][wo + 16 + lr][lg * 8];
            acc[p][0][0] = __builtin_amdgcn_mfma_f32_16x16x32_f16(a0, b0, acc[p][0][0], 0, 0, 0);
            acc[p][0][1] = __builtin_amdgcn_mfma_f32_16x16x32_f16(a0, b1, acc[p][0][1], 0, 0, 0);
            acc[p][1][0] = __builtin_amdgcn_mfma_f32_16x16x32_f16(a1, b0, acc[p][1][0], 0, 0, 0);
            acc[p][1][1] = __builtin_amdgcn_mfma_f32_16x16x32_f16(a1, b1, acc[p][1][1], 0, 0, 0);
        }
    }

    // Q, K: transpose via Ts then coalesced [n][c] writes
#pragma unroll
    for (int p = 0; p < 2; ++p) {
        __syncthreads();
#pragma unroll
        for (int so = 0; so < 2; ++so)
#pragma unroll
            for (int r = 0; r < 4; ++r) {
                int orow  = wo + so * 16 + lg * 4 + r;
                float bv_ = bs[p][o0 + orow];
#pragma unroll
                for (int sn = 0; sn < 2; ++sn)
                    Ts[orow][wn + sn * 16 + lr] = (f16)(acc[p][so][sn][r] + bv_);
            }
        __syncthreads();
        f16* dst = (p == 0) ? Qt : Kt;
        int n  = t >> 2;
        int o8 = (t & 3) * 16;
        f16 tmp[16];
#pragma unroll
        for (int u = 0; u < 16; ++u) tmp[u] = Ts[o8 + u][n];
        f16* g = dst + ((size_t)bb * ND + n0 + n) * CD + o0 + o8;
        *(f16x8*)g       = *(f16x8*)&tmp[0];
        *(f16x8*)(g + 8) = *(f16x8*)&tmp[8];
    }
    // V: direct [c][n] writes
#pragma unroll
    for (int so = 0; so < 2; ++so)
#pragma unroll
        for (int r = 0; r < 4; ++r) {
            int orow  = wo + so * 16 + lg * 4 + r;
            float bv_ = bv[o0 + orow];
#pragma unroll
            for (int sn = 0; sn < 2; ++sn) {
                int ncol = wn + sn * 16 + lr;
                Vb[((size_t)bb * CD + o0 + orow) * ND + n0 + ncol] =
                    (f16)(acc[2][so][sn][r] + bv_);
            }
        }
}

// ============================================================================
// Kernel 2: flash attention, split-K (template KSN), 32x32x16 MFMA.
// 4 waves x 32 queries.  KVB=32 keys/iter, double-buffered, 2 blocks/CU.
// SWAPPED QK^T as one 32x32 tile/wave: lane-local softmax (2 shfls).
// K read uses PER-LANE XOR-swizzled addresses (content at each MFMA k-slot
// stays uniform across lanes — required for correctness; r12's physical-
// chunk iteration violated this).  P->PV operand via cvt_pkrtz +
// v_permlane32_swap (equivalent to r11's verified select table).
// Defer-max THR=5.  D-layout (m101): col=lane&31, row=(r&3)+8*(r>>2)+4*hi.
// ============================================================================
template<int KSN>
__global__ __launch_bounds__(256, 2)
void k_attn(const f16* __restrict__ Qt, const f16* __restrict__ Kt,
            const f16* __restrict__ Vb, f16* __restrict__ Op,
            float* __restrict__ ml)
{
    __shared__ f16 Ks[2][32 * 256];   // [buf][row][chunk16B ^ (row&7)]  2x16 KB
    __shared__ f16 Vs[2][256 * 32];   // [buf][c][chunk16B ^ ((c>>1)&3)] 2x16 KB

    const int t   = threadIdx.x;
    const int w   = t >> 6;          // 0..3
    const int l   = t & 63;
    const int q32 = l & 31;          // this lane's query column / K row
    const int hi  = l >> 5;          // 0/1 half

    // ---- XCD-pinned decode ----
    const int bid = blockIdx.x;
    int bb, ks, qi;
    if constexpr (KSN == 8) {
        int xcd = bid & 7;
        bb = xcd & 1;
        ks = (xcd >> 1) | ((bid >> 8) << 2);
        qi = (bid >> 3) & 31;
    } else {   // KSN == 4
        bb = bid & 1;
        ks = (bid >> 1) & 3;
        qi = bid >> 3;
    }
    const int q0 = qi * 128 + w * 32;

    // K-row swizzle constants (row = q32): chunk (2n+hi)^s3 = 2*(n^t2) + hp
    const int s3 = q32 & 7;
    const int t2 = s3 >> 1;
    const int hp = hi ^ (s3 & 1);
    const int kb2 = q32 * 256 + hp * 8;     // per-lane K LDS base (elements)

    // Q fragments: qf[n] = logical chunk 2n+hi (channels n*16+hi*8 .. +7)
    f16x8 qf[16];
#pragma unroll
    for (int n = 0; n < 16; ++n)
        qf[n] = *(const f16x8*)(Qt + ((size_t)bb * ND + q0 + q32) * CD + n * 16 + hi * 8);

    // V per-lane constants (sw independent of cc since 32*cc ≡ 0 mod 8)
    const int sw  = (q32 >> 1) & 3;
    const int vb0 = q32 * 32 + (hi ^ sw) * 8;
    const int vb1 = q32 * 32 + ((2 + hi) ^ sw) * 8;

    f32x16 oacc[8] = {};      // 8 c-chunks of 32 rows; col=q32
    float row_m = -3.0e38f, row_l = 0.f;

    const int kv0 = ks * (ND / KSN);
    const f16* ktb = Kt + (size_t)bb * ND * CD;
    const f16* vbb = Vb + (size_t)bb * CD * ND;

    // per-lane loop-invariant staging offsets (elements)
    int koff[4], voff[4];
#pragma unroll
    for (int j = 0; j < 4; ++j) {
        int v   = (w * 4 + j) * 64 + l;
        int row = v >> 5;
        int ch  = (v & 31) ^ (row & 7);
        koff[j] = row * CD + ch * 8;
        int c   = v >> 2;
        int u   = (v & 3) ^ ((c >> 1) & 3);
        voff[j] = c * ND + u * 8;
    }

    auto stage = [&](int m0, int bi) {
#pragma unroll
        for (int j = 0; j < 4; ++j)
            gl_lds16(ktb + (size_t)m0 * CD + koff[j], &Ks[bi][(w * 4 + j) * 512]);
#pragma unroll
        for (int j = 0; j < 4; ++j)
            gl_lds16(vbb + m0 + voff[j], &Vs[bi][(w * 4 + j) * 512]);
    };

    stage(kv0, 0);
    __syncthreads();    // drains vmcnt; tile 0 resident

    const int NIT = (ND / KSN) / KVB;
    for (int it = 0; it < NIT; ++it) {
        const int bi = it & 1;
        if (it + 1 < NIT) stage(kv0 + (it + 1) * KVB, bi ^ 1);

        // ---- QK^T: per-lane swizzled K addresses (kb2 + (n^t2)*16) ----
        f32x16 sa = {}, sb = {};
        __builtin_amdgcn_s_setprio(1);
#pragma unroll
        for (int n = 0; n < 16; n += 2) {
            f16x8 ka = *(const f16x8*)&Ks[bi][kb2 + ((n ^ t2) << 4)];
            f16x8 kb = *(const f16x8*)&Ks[bi][kb2 + (((n + 1) ^ t2) << 4)];
            sa = __builtin_amdgcn_mfma_f32_32x32x16_f16(ka, qf[n],     sa, 0, 0, 0);
            sb = __builtin_amdgcn_mfma_f32_32x32x16_f16(kb, qf[n + 1], sb, 0, 0, 0);
        }
        __builtin_amdgcn_s_setprio(0);

        // ---- lane-local online softmax (defer-max THR=5) ----
        float p[16];
#pragma unroll
        for (int r = 0; r < 16; ++r) p[r] = sa[r] + sb[r];
        float pm = p[0];
#pragma unroll
        for (int r = 1; r < 16; ++r) pm = fmaxf(pm, p[r]);
        pm = fmaxf(pm, __shfl_xor(pm, 32));
        bool need = (pm > row_m + 5.0f);
        float nm  = need ? pm : row_m;
#pragma unroll
        for (int r = 0; r < 16; ++r) p[r] = __expf(p[r] - nm);
        float ps = 0.f;
#pragma unroll
        for (int r = 0; r < 16; ++r) ps += p[r];
        ps += __shfl_xor(ps, 32);
        if (__any(need)) {
            float sc = __expf(row_m - nm);   // == 1 for lanes w/o change
            row_l = row_l * sc + ps;
#pragma unroll
            for (int cc = 0; cc < 8; ++cc)
#pragma unroll
                for (int r = 0; r < 16; ++r) oacc[cc][r] *= sc;
        } else {
            row_l += ps;
        }
        row_m = nm;

        // ---- P -> PV B-operand via cvt_pkrtz + permlane32_swap ----
        // (equivalent to r11's verified ov/select table: a.hi <-> c.lo)
        unsigned int wv[8];
#pragma unroll
        for (int c = 0; c < 4; ++c) {
            h16x2 a = __builtin_amdgcn_cvt_pkrtz(p[4 * c],     p[4 * c + 1]);
            h16x2 b = __builtin_amdgcn_cvt_pkrtz(p[4 * c + 2], p[4 * c + 3]);
            wv[2 * c]     = __builtin_bit_cast(unsigned int, a);
            wv[2 * c + 1] = __builtin_bit_cast(unsigned int, b);
        }
        f16x8 pb[2];
#pragma unroll
        for (int j = 0; j < 2; ++j) {
            unsigned int a0 = wv[4 * j],     c0 = wv[4 * j + 2];
            unsigned int a1 = wv[4 * j + 1], c1 = wv[4 * j + 3];
            asm volatile("v_permlane32_swap_b32 %0, %1" : "+v"(a0), "+v"(c0));
            asm volatile("v_permlane32_swap_b32 %0, %1" : "+v"(a1), "+v"(c1));
            u32x4 bw = { a0, a1, c0, c1 };
            pb[j] = __builtin_bit_cast(f16x8, bw);
        }

        // ---- PV: O[c][q] += V[c][m] * P[m][q], 8 c-chunks x 2 m-halves ----
        __builtin_amdgcn_s_setprio(1);
#pragma unroll
        for (int cc = 0; cc < 8; ++cc) {
            f16x8 v0 = *(const f16x8*)&Vs[bi][cc * 1024 + vb0];
            f16x8 v1 = *(const f16x8*)&Vs[bi][cc * 1024 + vb1];
            oacc[cc] = __builtin_amdgcn_mfma_f32_32x32x16_f16(v0, pb[0], oacc[cc], 0, 0, 0);
            oacc[cc] = __builtin_amdgcn_mfma_f32_32x32x16_f16(v1, pb[1], oacc[cc], 0, 0, 0);
        }
        __builtin_amdgcn_s_setprio(0);
        __syncthreads();   // drains stage(it+1); frees buffers for next iter
    }

    // ---- write unnormalized partial + (m,l) ----
#pragma unroll
    for (int cc = 0; cc < 8; ++cc)
#pragma unroll
        for (int r = 0; r < 16; ++r) {
            int cch = cc * 32 + (r & 3) + 8 * (r >> 2) + 4 * hi;
            Op[(((size_t)ks * 2 + bb) * CD + cch) * ND + q0 + q32] = (f16)oacc[cc][r];
        }
    if (l < 32) {
        int n = q0 + l;
        ml[((ks * 2 + bb) * 2 + 0) * ND + n] = row_m;
        ml[((ks * 2 + bb) * 2 + 1) * ND + n] = row_l;
    }
}

// ============================================================================
// Kernel 2b-i: per-n combine weights  wq[ks][b][n] = exp(m-M)/L
// ============================================================================
template<int KSN>
__global__ __launch_bounds__(256)
void k_ml(const float* __restrict__ ml, float* __restrict__ wq)
{
    int i = blockIdx.x * 256 + threadIdx.x;   // i over B*ND
    int b = i / ND, n = i % ND;
    float m[KSN], lv[KSN];
#pragma unroll
    for (int ks = 0; ks < KSN; ++ks) {
        m[ks]  = ml[((ks * 2 + b) * 2 + 0) * ND + n];
        lv[ks] = ml[((ks * 2 + b) * 2 + 1) * ND + n];
    }
    float M = m[0];
#pragma unroll
    for (int ks = 1; ks < KSN; ++ks) M = fmaxf(M, m[ks]);
    float wgt[KSN], L = 0.f;
#pragma unroll
    for (int ks = 0; ks < KSN; ++ks) { wgt[ks] = __expf(m[ks] - M); L += wgt[ks] * lv[ks]; }
    float inv = 1.0f / L;
#pragma unroll
    for (int ks = 0; ks < KSN; ++ks)
        wq[(ks * 2 + b) * ND + n] = wgt[ks] * inv;
}

// ============================================================================
// Kernel 2b-ii: combine split-K partials -> Hb[b][c][n] f16 (vectorized)
// ============================================================================
template<int KSN>
__global__ __launch_bounds__(256)
void k_comb(const f16* __restrict__ Op, const float* __restrict__ wq,
            f16* __restrict__ Hb)
{
    size_t i = (size_t)blockIdx.x * 256 + threadIdx.x;   // one f16x8 each
    int n0 = (int)(i % (ND / 8)) * 8;
    int c  = (int)((i / (ND / 8)) % CD);
    int b  = (int)(i / ((size_t)CD * (ND / 8)));

    float acc[8] = {};
#pragma unroll
    for (int ks = 0; ks < KSN; ++ks) {
        f16x8 o = *(const f16x8*)(Op + (((size_t)ks * 2 + b) * CD + c) * ND + n0);
        const float* wp = wq + (ks * 2 + b) * ND + n0;
        float4 w0 = *(const float4*)wp;
        float4 w1 = *(const float4*)(wp + 4);
        acc[0] += w0.x * (float)o[0]; acc[1] += w0.y * (float)o[1];
        acc[2] += w0.z * (float)o[2]; acc[3] += w0.w * (float)o[3];
        acc[4] += w1.x * (float)o[4]; acc[5] += w1.y * (float)o[5];
        acc[6] += w1.z * (float)o[6]; acc[7] += w1.w * (float)o[7];
    }
    f16x8 h;
#pragma unroll
    for (int u = 0; u < 8; ++u) h[u] = (f16)acc[u];
    *(f16x8*)(Hb + ((size_t)b * CD + c) * ND + n0) = h;
}

// ============================================================================
// Kernel 3: output projection + residual.  Yh = f16(Wo@H + bo + x)
// Emits deterministic per-block GroupNorm partials (f32, pre-rounding).
// ============================================================================
__global__ __launch_bounds__(256)
void k_proj_o(const f16* __restrict__ Hb, const float* __restrict__ Wo,
              const float* __restrict__ bo, const float* __restrict__ x,
              f16* __restrict__ Yh, float* __restrict__ part)
{
    __shared__ f16 As[64][40];
    __shared__ f16 Bs[64][40];
    __shared__ float rs[4][2][2][2];   // [wave][so][lg>>1][{s,s2}]

    const int t  = threadIdx.x;
    const int n0 = blockIdx.x * 64;
    const int o0 = blockIdx.y * 64;
    const int bb = blockIdx.z;

    const int w  = t >> 6;
    const int l  = t & 63;
    const int lr = l & 15;
    const int lg = l >> 4;
    const int wo = (w >> 1) * 32;
    const int wn = (w & 1) * 32;

    const int sl = t & 63;
    const int k8 = (t >> 6) * 8;

    f32x4 acc[2][2] = {};

    for (int ck = 0; ck < CD; ck += 32) {
        __syncthreads();
        {
            const float* s = Wo + (size_t)(o0 + sl) * CD + ck + k8;
            f16x8 v;
#pragma unroll
            for (int u = 0; u < 8; ++u) v[u] = (f16)s[u];
            *(f16x8*)&As[sl][k8] = v;
        }
        {
            const f16* s = Hb + ((size_t)bb * CD + ck + k8) * ND + n0 + sl;
            f16x8 v;
#pragma unroll
            for (int u = 0; u < 8; ++u) v[u] = s[(size_t)u * ND];
            *(f16x8*)&Bs[sl][k8] = v;
        }
        __syncthreads();
        f16x8 a0 = *(const f16x8*)&As[wo + lr][lg * 8];
        f16x8 a1 = *(const f16x8*)&As[wo + 16 + lr][lg * 8];
        f16x8 b0 = *(const f16x8*)&Bs[wn + lr][lg * 8];
        f16x8 b1 = *(const f16x8*)&Bs[wn + 16 + lr][lg * 8];
        acc[0][0] = __builtin_amdgcn_mfma_f32_16x16x32_f16(a0, b0, acc[0][0], 0, 0, 0);
        acc[0][1] = __builtin_amdgcn_mfma_f32_16x16x32_f16(a0, b1, acc[0][1], 0, 0, 0);
        acc[1][0] = __builtin_amdgcn_mfma_f32_16x16x32_f16(a1, b0, acc[1][0], 0, 0, 0);
        acc[1][1] = __builtin_amdgcn_mfma_f32_16x16x32_f16(a1, b1, acc[1][1], 0, 0, 0);
    }

#pragma unroll
    for (int so = 0; so < 2; ++so) {
        float ls = 0.f, ls2 = 0.f;
#pragma unroll
        for (int r = 0; r < 4; ++r) {
            int orow  = wo + so * 16 + lg * 4 + r;
            float bv_ = bo[o0 + orow];
#pragma unroll
            for (int sn = 0; sn < 2; ++sn) {
                int ncol   = wn + sn * 16 + lr;
                size_t idx = ((size_t)bb * CD + o0 + orow) * ND + n0 + ncol;
                float v = acc[so][sn][r] + bv_ + x[idx];
                Yh[idx] = (f16)v;
                ls  += v;
                ls2 += v * v;
            }
        }
        // deterministic reduce over lanes sharing the same group
#pragma unroll
        for (int m = 1; m <= 16; m <<= 1) {
            ls  += __shfl_xor(ls, m);
            ls2 += __shfl_xor(ls2, m);
        }
        if ((l & 31) == 0) {
            rs[w][so][l >> 5][0] = ls;
            rs[w][so][l >> 5][1] = ls2;
        }
    }
    __syncthreads();
    if (t < 16) {
        int gl = t >> 1, st = t & 1;
        int a = gl >> 2, so = (gl >> 1) & 1, lh = gl & 1;
        float v = rs[2 * a][so][lh][st] + rs[2 * a + 1][so][lh][st];
        part[(((size_t)bb * GD + (o0 >> 3) + gl) * 64 + blockIdx.x) * 2 + st] = v;
    }
}

// ============================================================================
// Kernel 4: GroupNorm (from partials) + SiLU, single pass, f16 in / f32 out
// ============================================================================
__global__ __launch_bounds__(256)
void k_gn_silu(const f16* __restrict__ Yh, const float* __restrict__ part,
               const float* __restrict__ gamma, const float* __restrict__ beta,
               float* __restrict__ out)
{
    const int g  = blockIdx.x, b = blockIdx.y, nq = blockIdx.z;
    const int t  = threadIdx.x;

    __shared__ float mr[2];
    if (t < 64) {
        float s  = part[(((size_t)b * GD + g) * 64 + t) * 2 + 0];
        float s2 = part[(((size_t)b * GD + g) * 64 + t) * 2 + 1];
#pragma unroll
        for (int m = 1; m < 64; m <<= 1) {
            s  += __shfl_xor(s, m);
            s2 += __shfl_xor(s2, m);
        }
        if (t == 0) {
            float mean = s / 32768.f;
            float var  = s2 / 32768.f - mean * mean;
            mr[0] = mean;
            mr[1] = rsqrtf(var + 1e-5f);
        }
    }
    __syncthreads();
    const float mean = mr[0], rstd = mr[1];

    const size_t base = ((size_t)b * CD + g * 8) * ND;
    const f16x8* src = (const f16x8*)(Yh + base);

    for (int i = t; i < 1024; i += 256) {
        int ch = i >> 7;
        int nn = i & 127;
        f16x8 v = src[ch * (ND / 8) + nq * 128 + nn];
        int c = g * 8 + ch;
        float ga = gamma[c], be = beta[c];
        float ob[8];
#pragma unroll
        for (int u = 0; u < 8; ++u) {
            float yn = ((float)v[u] - mean) * rstd * ga + be;
            float sg = 1.0f / (1.0f + __expf(-yn));
            ob[u] = yn * sg;
        }
        float* dp = out + base + (size_t)ch * ND + nq * 1024 + nn * 8;
        *(float4*)dp       = *(float4*)&ob[0];
        *(float4*)(dp + 4) = *(float4*)&ob[4];
    }
}

// ============================================================================
extern "C" void kernel_launch(void* const* d_in, const int* in_sizes, int n_in,
                              void* d_out, int out_size, void* d_ws, size_t ws_size,
                              hipStream_t stream)
{
    const float* x     = (const float*)d_in[0];
    const float* Wq    = (const float*)d_in[1];
    const float* bq    = (const float*)d_in[2];
    const float* Wk    = (const float*)d_in[3];
    const float* bk    = (const float*)d_in[4];
    const float* Wv    = (const float*)d_in[5];
    const float* bv    = (const float*)d_in[6];
    const float* Wo    = (const float*)d_in[7];
    const float* bo    = (const float*)d_in[8];
    const float* gamma = (const float*)d_in[9];
    const float* beta  = (const float*)d_in[10];

    char* ws = (char*)d_ws;
    f16* Qt = (f16*)(ws);                    //  0..4 MiB   [B][N][C]
    f16* Kt = (f16*)(ws + (4u << 20));       //  4..8 MiB   [B][N][C]
    f16* Vb = (f16*)(ws + (8u << 20));       //  8..12 MiB  [B][C][N]
    f16* Hb = (f16*)(ws + (12u << 20));      // 12..16 MiB  [B][C][N]
    f16* Op = (f16*)(ws + (16u << 20));      // 16.. MiB    [KSN][B][C][N]
    f16* Yh = (f16*)(ws + (16u << 20));      // reuses Op region after combine

    const bool big = ws_size >= (50ull << 20);

    k_proj_qkv<<<dim3(64, 4, 2), 256, 0, stream>>>(x, Wq, bq, Wk, bk, Wv, bv, Qt, Kt, Vb);

    if (big) {
        constexpr int KSN = 8;
        float* ml   = (float*)(ws + (48u << 20));                 // 512 KB
        float* wq   = (float*)(ws + (48u << 20) + (768u << 10));  // 256 KB
        float* part = (float*)(ws + (49u << 20) + (512u << 10));  // 32 KB
        k_attn<KSN><<<dim3(32 * KSN * 2), 256, 0, stream>>>(Qt, Kt, Vb, Op, ml);
        k_ml<KSN><<<dim3((2 * ND) / 256), 256, 0, stream>>>(ml, wq);
        k_comb<KSN><<<dim3((2 * CD * ND / 8) / 256), 256, 0, stream>>>(Op, wq, Hb);
        k_proj_o<<<dim3(64, 4, 2), 256, 0, stream>>>(Hb, Wo, bo, x, Yh, part);
        k_gn_silu<<<dim3(GD, 2, 4), 256, 0, stream>>>(Yh, part, gamma, beta, (float*)d_out);
    } else {
        constexpr int KSN = 4;
        float* ml   = (float*)(ws + (32u << 20));                 // 256 KB
        float* wq   = (float*)(ws + (32u << 20) + (512u << 10));  // 128 KB
        float* part = (float*)(ws + (33u << 20));                 // 32 KB
        k_attn<KSN><<<dim3(32 * KSN * 2), 256, 0, stream>>>(Qt, Kt, Vb, Op, ml);
        k_ml<KSN><<<dim3((2 * ND) / 256), 256, 0, stream>>>(ml, wq);
        k_comb<KSN><<<dim3((2 * CD * ND / 8) / 256), 256, 0, stream>>>(Op, wq, Hb);
        k_proj_o<<<dim3(64, 4, 2), 256, 0, stream>>>(Hb, Wo, bo, x, Yh, part);
        k_gn_silu<<<dim3(GD, 2, 4), 256, 0, stream>>>(Yh, part, gamma, beta, (float*)d_out);
    }
}

// Round 14
// 102.267 us; speedup vs baseline: 1.0938x; 1.0200x over previous
//
#include <hip/hip_runtime.h>
#include <hip/hip_bf16.h>

typedef _Float16 f16;
typedef __attribute__((ext_vector_type(2))) __fp16 h16x2;   // cvt_pkrtz return type
typedef __attribute__((ext_vector_type(4))) _Float16 f16x4;
typedef __attribute__((ext_vector_type(8))) _Float16 f16x8;
typedef __attribute__((ext_vector_type(4))) float f32x4;
typedef __attribute__((ext_vector_type(16))) float f32x16;
typedef __attribute__((ext_vector_type(4))) unsigned int u32x4;

#define CD 256
#define ND 4096
#define GD 32
#define KVB 32          // keys per iteration

// async global->LDS, 16B per lane, lds dest must be wave-uniform base
__device__ __forceinline__ void gl_lds16(const f16* g, f16* l) {
    __builtin_amdgcn_global_load_lds(
        (const __attribute__((address_space(1))) unsigned int*)g,
        (__attribute__((address_space(3))) unsigned int*)l,
        16, 0, 0);
}

// ============================================================================
// Kernel 0: pre-convert W matrices to f16.  Wh = [Wq|Wk|Wv|Wo] f16, 512 KB.
// ============================================================================
__global__ __launch_bounds__(256)
void k_prep(const float* __restrict__ Wq, const float* __restrict__ Wk,
            const float* __restrict__ Wv, const float* __restrict__ Wo,
            f16* __restrict__ Wh)
{
    const float* Ws[4] = { Wq, Wk, Wv, Wo };
    int i = blockIdx.x * 256 + threadIdx.x;       // over 4*65536/8 = 32768
    int p = i >> 13;                              // 8192 f16x8 per matrix
    int e = (i & 8191) * 8;
    const float* s = Ws[p] + e;
    float4 v0 = *(const float4*)s;
    float4 v1 = *(const float4*)(s + 4);
    f16x8 h = { (f16)v0.x, (f16)v0.y, (f16)v0.z, (f16)v0.w,
                (f16)v1.x, (f16)v1.y, (f16)v1.z, (f16)v1.w };
    *(f16x8*)(Wh + p * 65536 + e) = h;
}

// ============================================================================
// Kernel 1: fused QKV projection, BK=64, A staged from pre-converted Wh.
// p[b,o,n] = sum_c W[o,c] x[b,c,n] + bias[o]
// Q,K written TRANSPOSED [b][n][c] f16; V natural [b][c][n] f16.
// ============================================================================
__global__ __launch_bounds__(256)
void k_proj_qkv(const float* __restrict__ x, const f16* __restrict__ Wh,
                const float* __restrict__ bq, const float* __restrict__ bk,
                const float* __restrict__ bv,
                f16* __restrict__ Qt, f16* __restrict__ Kt, f16* __restrict__ Vb)
{
    __shared__ f16 As[3][64][72];
    __shared__ f16 Bs[64][72];
    __shared__ f16 Ts[64][72];

    const int t  = threadIdx.x;
    const int n0 = blockIdx.x * 64;
    const int o0 = blockIdx.y * 64;
    const int bb = blockIdx.z;

    const float* bs[3] = { bq, bk, bv };

    const int w  = t >> 6;
    const int l  = t & 63;
    const int lr = l & 15;
    const int lg = l >> 4;
    const int wo = (w >> 1) * 32;
    const int wn = (w & 1) * 32;

    const int sl  = t & 63;
    const int kc8 = (t >> 6) * 16;    // 16-element k chunk base

    f32x4 acc[3][2][2] = {};

    for (int ck = 0; ck < CD; ck += 64) {
        __syncthreads();
#pragma unroll
        for (int p = 0; p < 3; ++p) {   // A: f16 vector copies, no cvt
            const f16* s = Wh + p * 65536 + (size_t)(o0 + sl) * CD + ck + kc8;
            *(f16x8*)&As[p][sl][kc8]     = *(const f16x8*)s;
            *(f16x8*)&As[p][sl][kc8 + 8] = *(const f16x8*)(s + 8);
        }
        {   // B: 16 strided f32 loads + cvt (coalesced across lanes)
            const float* s = x + ((size_t)bb * CD + ck + kc8) * ND + n0 + sl;
#pragma unroll
            for (int u = 0; u < 16; ++u)
                Bs[sl][kc8 + u] = (f16)s[(size_t)u * ND];
        }
        __syncthreads();
#pragma unroll
        for (int kk = 0; kk < 2; ++kk) {
            f16x8 b0 = *(const f16x8*)&Bs[wn + lr][kk * 32 + lg * 8];
            f16x8 b1 = *(const f16x8*)&Bs[wn + 16 + lr][kk * 32 + lg * 8];
#pragma unroll
            for (int p = 0; p < 3; ++p) {
                f16x8 a0 = *(const f16x8*)&As[p][wo + lr][kk * 32 + lg * 8];
                f16x8 a1 = *(const f16x8*)&As[p][wo + 16 + lr][kk * 32 + lg * 8];
                acc[p][0][0] = __builtin_amdgcn_mfma_f32_16x16x32_f16(a0, b0, acc[p][0][0], 0, 0, 0);
                acc[p][0][1] = __builtin_amdgcn_mfma_f32_16x16x32_f16(a0, b1, acc[p][0][1], 0, 0, 0);
                acc[p][1][0] = __builtin_amdgcn_mfma_f32_16x16x32_f16(a1, b0, acc[p][1][0], 0, 0, 0);
                acc[p][1][1] = __builtin_amdgcn_mfma_f32_16x16x32_f16(a1, b1, acc[p][1][1], 0, 0, 0);
            }
        }
    }

    // Q, K: transpose via Ts then coalesced [n][c] writes
#pragma unroll
    for (int p = 0; p < 2; ++p) {
        __syncthreads();
#pragma unroll
        for (int so = 0; so < 2; ++so)
#pragma unroll
            for (int r = 0; r < 4; ++r) {
                int orow  = wo + so * 16 + lg * 4 + r;
                float bv_ = bs[p][o0 + orow];
#pragma unroll
                for (int sn = 0; sn < 2; ++sn)
                    Ts[orow][wn + sn * 16 + lr] = (f16)(acc[p][so][sn][r] + bv_);
            }
        __syncthreads();
        f16* dst = (p == 0) ? Qt : Kt;
        int n  = t >> 2;
        int o8 = (t & 3) * 16;
        f16 tmp[16];
#pragma unroll
        for (int u = 0; u < 16; ++u) tmp[u] = Ts[o8 + u][n];
        f16* g = dst + ((size_t)bb * ND + n0 + n) * CD + o0 + o8;
        *(f16x8*)g       = *(f16x8*)&tmp[0];
        *(f16x8*)(g + 8) = *(f16x8*)&tmp[8];
    }
    // V: direct [c][n] writes
#pragma unroll
    for (int so = 0; so < 2; ++so)
#pragma unroll
        for (int r = 0; r < 4; ++r) {
            int orow  = wo + so * 16 + lg * 4 + r;
            float bv_ = bv[o0 + orow];
#pragma unroll
            for (int sn = 0; sn < 2; ++sn) {
                int ncol = wn + sn * 16 + lr;
                Vb[((size_t)bb * CD + o0 + orow) * ND + n0 + ncol] =
                    (f16)(acc[2][so][sn][r] + bv_);
            }
        }
}

// ============================================================================
// Kernel 2: flash attention, split-K (template KSN), 32x32x16 MFMA.
// (unchanged from round 13 — verified)
// ============================================================================
template<int KSN>
__global__ __launch_bounds__(256, 2)
void k_attn(const f16* __restrict__ Qt, const f16* __restrict__ Kt,
            const f16* __restrict__ Vb, f16* __restrict__ Op,
            float* __restrict__ ml)
{
    __shared__ f16 Ks[2][32 * 256];   // [buf][row][chunk16B ^ (row&7)]  2x16 KB
    __shared__ f16 Vs[2][256 * 32];   // [buf][c][chunk16B ^ ((c>>1)&3)] 2x16 KB

    const int t   = threadIdx.x;
    const int w   = t >> 6;          // 0..3
    const int l   = t & 63;
    const int q32 = l & 31;          // this lane's query column / K row
    const int hi  = l >> 5;          // 0/1 half

    // ---- XCD-pinned decode ----
    const int bid = blockIdx.x;
    int bb, ks, qi;
    if constexpr (KSN == 8) {
        int xcd = bid & 7;
        bb = xcd & 1;
        ks = (xcd >> 1) | ((bid >> 8) << 2);
        qi = (bid >> 3) & 31;
    } else {   // KSN == 4
        bb = bid & 1;
        ks = (bid >> 1) & 3;
        qi = bid >> 3;
    }
    const int q0 = qi * 128 + w * 32;

    // K-row swizzle constants (row = q32): chunk (2n+hi)^s3 = 2*(n^t2) + hp
    const int s3 = q32 & 7;
    const int t2 = s3 >> 1;
    const int hp = hi ^ (s3 & 1);
    const int kb2 = q32 * 256 + hp * 8;     // per-lane K LDS base (elements)

    // Q fragments: qf[n] = logical chunk 2n+hi (channels n*16+hi*8 .. +7)
    f16x8 qf[16];
#pragma unroll
    for (int n = 0; n < 16; ++n)
        qf[n] = *(const f16x8*)(Qt + ((size_t)bb * ND + q0 + q32) * CD + n * 16 + hi * 8);

    // V per-lane constants
    const int sw  = (q32 >> 1) & 3;
    const int vb0 = q32 * 32 + (hi ^ sw) * 8;
    const int vb1 = q32 * 32 + ((2 + hi) ^ sw) * 8;

    f32x16 oacc[8] = {};      // 8 c-chunks of 32 rows; col=q32
    float row_m = -3.0e38f, row_l = 0.f;

    const int kv0 = ks * (ND / KSN);
    const f16* ktb = Kt + (size_t)bb * ND * CD;
    const f16* vbb = Vb + (size_t)bb * CD * ND;

    // per-lane loop-invariant staging offsets (elements)
    int koff[4], voff[4];
#pragma unroll
    for (int j = 0; j < 4; ++j) {
        int v   = (w * 4 + j) * 64 + l;
        int row = v >> 5;
        int ch  = (v & 31) ^ (row & 7);
        koff[j] = row * CD + ch * 8;
        int c   = v >> 2;
        int u   = (v & 3) ^ ((c >> 1) & 3);
        voff[j] = c * ND + u * 8;
    }

    auto stage = [&](int m0, int bi) {
#pragma unroll
        for (int j = 0; j < 4; ++j)
            gl_lds16(ktb + (size_t)m0 * CD + koff[j], &Ks[bi][(w * 4 + j) * 512]);
#pragma unroll
        for (int j = 0; j < 4; ++j)
            gl_lds16(vbb + m0 + voff[j], &Vs[bi][(w * 4 + j) * 512]);
    };

    stage(kv0, 0);
    __syncthreads();    // drains vmcnt; tile 0 resident

    const int NIT = (ND / KSN) / KVB;
    for (int it = 0; it < NIT; ++it) {
        const int bi = it & 1;
        if (it + 1 < NIT) stage(kv0 + (it + 1) * KVB, bi ^ 1);

        // ---- QK^T: per-lane swizzled K addresses (kb2 + (n^t2)*16) ----
        f32x16 sa = {}, sb = {};
        __builtin_amdgcn_s_setprio(1);
#pragma unroll
        for (int n = 0; n < 16; n += 2) {
            f16x8 ka = *(const f16x8*)&Ks[bi][kb2 + ((n ^ t2) << 4)];
            f16x8 kb = *(const f16x8*)&Ks[bi][kb2 + (((n + 1) ^ t2) << 4)];
            sa = __builtin_amdgcn_mfma_f32_32x32x16_f16(ka, qf[n],     sa, 0, 0, 0);
            sb = __builtin_amdgcn_mfma_f32_32x32x16_f16(kb, qf[n + 1], sb, 0, 0, 0);
        }
        __builtin_amdgcn_s_setprio(0);

        // ---- lane-local online softmax (defer-max THR=5) ----
        float p[16];
#pragma unroll
        for (int r = 0; r < 16; ++r) p[r] = sa[r] + sb[r];
        float pm = p[0];
#pragma unroll
        for (int r = 1; r < 16; ++r) pm = fmaxf(pm, p[r]);
        pm = fmaxf(pm, __shfl_xor(pm, 32));
        bool need = (pm > row_m + 5.0f);
        float nm  = need ? pm : row_m;
#pragma unroll
        for (int r = 0; r < 16; ++r) p[r] = __expf(p[r] - nm);
        float ps = 0.f;
#pragma unroll
        for (int r = 0; r < 16; ++r) ps += p[r];
        ps += __shfl_xor(ps, 32);
        if (__any(need)) {
            float sc = __expf(row_m - nm);   // == 1 for lanes w/o change
            row_l = row_l * sc + ps;
#pragma unroll
            for (int cc = 0; cc < 8; ++cc)
#pragma unroll
                for (int r = 0; r < 16; ++r) oacc[cc][r] *= sc;
        } else {
            row_l += ps;
        }
        row_m = nm;

        // ---- P -> PV B-operand via cvt_pkrtz + permlane32_swap ----
        unsigned int wv[8];
#pragma unroll
        for (int c = 0; c < 4; ++c) {
            h16x2 a = __builtin_amdgcn_cvt_pkrtz(p[4 * c],     p[4 * c + 1]);
            h16x2 b = __builtin_amdgcn_cvt_pkrtz(p[4 * c + 2], p[4 * c + 3]);
            wv[2 * c]     = __builtin_bit_cast(unsigned int, a);
            wv[2 * c + 1] = __builtin_bit_cast(unsigned int, b);
        }
        f16x8 pb[2];
#pragma unroll
        for (int j = 0; j < 2; ++j) {
            unsigned int a0 = wv[4 * j],     c0 = wv[4 * j + 2];
            unsigned int a1 = wv[4 * j + 1], c1 = wv[4 * j + 3];
            asm volatile("v_permlane32_swap_b32 %0, %1" : "+v"(a0), "+v"(c0));
            asm volatile("v_permlane32_swap_b32 %0, %1" : "+v"(a1), "+v"(c1));
            u32x4 bw = { a0, a1, c0, c1 };
            pb[j] = __builtin_bit_cast(f16x8, bw);
        }

        // ---- PV: O[c][q] += V[c][m] * P[m][q], 8 c-chunks x 2 m-halves ----
        __builtin_amdgcn_s_setprio(1);
#pragma unroll
        for (int cc = 0; cc < 8; ++cc) {
            f16x8 v0 = *(const f16x8*)&Vs[bi][cc * 1024 + vb0];
            f16x8 v1 = *(const f16x8*)&Vs[bi][cc * 1024 + vb1];
            oacc[cc] = __builtin_amdgcn_mfma_f32_32x32x16_f16(v0, pb[0], oacc[cc], 0, 0, 0);
            oacc[cc] = __builtin_amdgcn_mfma_f32_32x32x16_f16(v1, pb[1], oacc[cc], 0, 0, 0);
        }
        __builtin_amdgcn_s_setprio(0);
        __syncthreads();   // drains stage(it+1); frees buffers for next iter
    }

    // ---- write unnormalized partial + (m,l) ----
#pragma unroll
    for (int cc = 0; cc < 8; ++cc)
#pragma unroll
        for (int r = 0; r < 16; ++r) {
            int cch = cc * 32 + (r & 3) + 8 * (r >> 2) + 4 * hi;
            Op[(((size_t)ks * 2 + bb) * CD + cch) * ND + q0 + q32] = (f16)oacc[cc][r];
        }
    if (l < 32) {
        int n = q0 + l;
        ml[((ks * 2 + bb) * 2 + 0) * ND + n] = row_m;
        ml[((ks * 2 + bb) * 2 + 1) * ND + n] = row_l;
    }
}

// ============================================================================
// Kernel 2b-i: per-n combine weights  wq[ks][b][n] = exp(m-M)/L
// ============================================================================
template<int KSN>
__global__ __launch_bounds__(256)
void k_ml(const float* __restrict__ ml, float* __restrict__ wq)
{
    int i = blockIdx.x * 256 + threadIdx.x;   // i over B*ND
    int b = i / ND, n = i % ND;
    float m[KSN], lv[KSN];
#pragma unroll
    for (int ks = 0; ks < KSN; ++ks) {
        m[ks]  = ml[((ks * 2 + b) * 2 + 0) * ND + n];
        lv[ks] = ml[((ks * 2 + b) * 2 + 1) * ND + n];
    }
    float M = m[0];
#pragma unroll
    for (int ks = 1; ks < KSN; ++ks) M = fmaxf(M, m[ks]);
    float wgt[KSN], L = 0.f;
#pragma unroll
    for (int ks = 0; ks < KSN; ++ks) { wgt[ks] = __expf(m[ks] - M); L += wgt[ks] * lv[ks]; }
    float inv = 1.0f / L;
#pragma unroll
    for (int ks = 0; ks < KSN; ++ks)
        wq[(ks * 2 + b) * ND + n] = wgt[ks] * inv;
}

// ============================================================================
// Kernel 2b-ii: combine split-K partials -> Hb[b][c][n] f16 (vectorized)
// ============================================================================
template<int KSN>
__global__ __launch_bounds__(256)
void k_comb(const f16* __restrict__ Op, const float* __restrict__ wq,
            f16* __restrict__ Hb)
{
    size_t i = (size_t)blockIdx.x * 256 + threadIdx.x;   // one f16x8 each
    int n0 = (int)(i % (ND / 8)) * 8;
    int c  = (int)((i / (ND / 8)) % CD);
    int b  = (int)(i / ((size_t)CD * (ND / 8)));

    float acc[8] = {};
#pragma unroll
    for (int ks = 0; ks < KSN; ++ks) {
        f16x8 o = *(const f16x8*)(Op + (((size_t)ks * 2 + b) * CD + c) * ND + n0);
        const float* wp = wq + (ks * 2 + b) * ND + n0;
        float4 w0 = *(const float4*)wp;
        float4 w1 = *(const float4*)(wp + 4);
        acc[0] += w0.x * (float)o[0]; acc[1] += w0.y * (float)o[1];
        acc[2] += w0.z * (float)o[2]; acc[3] += w0.w * (float)o[3];
        acc[4] += w1.x * (float)o[4]; acc[5] += w1.y * (float)o[5];
        acc[6] += w1.z * (float)o[6]; acc[7] += w1.w * (float)o[7];
    }
    f16x8 h;
#pragma unroll
    for (int u = 0; u < 8; ++u) h[u] = (f16)acc[u];
    *(f16x8*)(Hb + ((size_t)b * CD + c) * ND + n0) = h;
}

// ============================================================================
// Kernel 3: output projection + residual, BK=64, A from Wh[3].
// Yh = f16(Wo@H + bo + x); emits deterministic GroupNorm partials.
// ============================================================================
__global__ __launch_bounds__(256)
void k_proj_o(const f16* __restrict__ Hb, const f16* __restrict__ Wh,
              const float* __restrict__ bo, const float* __restrict__ x,
              f16* __restrict__ Yh, float* __restrict__ part)
{
    __shared__ f16 As[64][72];
    __shared__ f16 Bs[64][72];
    __shared__ float rs[4][2][2][2];   // [wave][so][lg>>1][{s,s2}]

    const int t  = threadIdx.x;
    const int n0 = blockIdx.x * 64;
    const int o0 = blockIdx.y * 64;
    const int bb = blockIdx.z;

    const int w  = t >> 6;
    const int l  = t & 63;
    const int lr = l & 15;
    const int lg = l >> 4;
    const int wo = (w >> 1) * 32;
    const int wn = (w & 1) * 32;

    const int sl  = t & 63;
    const int kc8 = (t >> 6) * 16;

    const f16* Wo16 = Wh + 3 * 65536;

    f32x4 acc[2][2] = {};

    for (int ck = 0; ck < CD; ck += 64) {
        __syncthreads();
        {
            const f16* s = Wo16 + (size_t)(o0 + sl) * CD + ck + kc8;
            *(f16x8*)&As[sl][kc8]     = *(const f16x8*)s;
            *(f16x8*)&As[sl][kc8 + 8] = *(const f16x8*)(s + 8);
        }
        {
            const f16* s = Hb + ((size_t)bb * CD + ck + kc8) * ND + n0 + sl;
#pragma unroll
            for (int u = 0; u < 16; ++u)
                Bs[sl][kc8 + u] = s[(size_t)u * ND];
        }
        __syncthreads();
#pragma unroll
        for (int kk = 0; kk < 2; ++kk) {
            f16x8 a0 = *(const f16x8*)&As[wo + lr][kk * 32 + lg * 8];
            f16x8 a1 = *(const f16x8*)&As[wo + 16 + lr][kk * 32 + lg * 8];
            f16x8 b0 = *(const f16x8*)&Bs[wn + lr][kk * 32 + lg * 8];
            f16x8 b1 = *(const f16x8*)&Bs[wn + 16 + lr][kk * 32 + lg * 8];
            acc[0][0] = __builtin_amdgcn_mfma_f32_16x16x32_f16(a0, b0, acc[0][0], 0, 0, 0);
            acc[0][1] = __builtin_amdgcn_mfma_f32_16x16x32_f16(a0, b1, acc[0][1], 0, 0, 0);
            acc[1][0] = __builtin_amdgcn_mfma_f32_16x16x32_f16(a1, b0, acc[1][0], 0, 0, 0);
            acc[1][1] = __builtin_amdgcn_mfma_f32_16x16x32_f16(a1, b1, acc[1][1], 0, 0, 0);
        }
    }

#pragma unroll
    for (int so = 0; so < 2; ++so) {
        float ls = 0.f, ls2 = 0.f;
#pragma unroll
        for (int r = 0; r < 4; ++r) {
            int orow  = wo + so * 16 + lg * 4 + r;
            float bv_ = bo[o0 + orow];
#pragma unroll
            for (int sn = 0; sn < 2; ++sn) {
                int ncol   = wn + sn * 16 + lr;
                size_t idx = ((size_t)bb * CD + o0 + orow) * ND + n0 + ncol;
                float v = acc[so][sn][r] + bv_ + x[idx];
                Yh[idx] = (f16)v;
                ls  += v;
                ls2 += v * v;
            }
        }
        // deterministic reduce over lanes sharing the same group
#pragma unroll
        for (int m = 1; m <= 16; m <<= 1) {
            ls  += __shfl_xor(ls, m);
            ls2 += __shfl_xor(ls2, m);
        }
        if ((l & 31) == 0) {
            rs[w][so][l >> 5][0] = ls;
            rs[w][so][l >> 5][1] = ls2;
        }
    }
    __syncthreads();
    if (t < 16) {
        int gl = t >> 1, st = t & 1;
        int a = gl >> 2, so = (gl >> 1) & 1, lh = gl & 1;
        float v = rs[2 * a][so][lh][st] + rs[2 * a + 1][so][lh][st];
        part[(((size_t)bb * GD + (o0 >> 3) + gl) * 64 + blockIdx.x) * 2 + st] = v;
    }
}

// ============================================================================
// Kernel 4: GroupNorm (from partials) + SiLU, single pass, f16 in / f32 out
// ============================================================================
__global__ __launch_bounds__(256)
void k_gn_silu(const f16* __restrict__ Yh, const float* __restrict__ part,
               const float* __restrict__ gamma, const float* __restrict__ beta,
               float* __restrict__ out)
{
    const int g  = blockIdx.x, b = blockIdx.y, nq = blockIdx.z;
    const int t  = threadIdx.x;

    __shared__ float mr[2];
    if (t < 64) {
        float s  = part[(((size_t)b * GD + g) * 64 + t) * 2 + 0];
        float s2 = part[(((size_t)b * GD + g) * 64 + t) * 2 + 1];
#pragma unroll
        for (int m = 1; m < 64; m <<= 1) {
            s  += __shfl_xor(s, m);
            s2 += __shfl_xor(s2, m);
        }
        if (t == 0) {
            float mean = s / 32768.f;
            float var  = s2 / 32768.f - mean * mean;
            mr[0] = mean;
            mr[1] = rsqrtf(var + 1e-5f);
        }
    }
    __syncthreads();
    const float mean = mr[0], rstd = mr[1];

    const size_t base = ((size_t)b * CD + g * 8) * ND;
    const f16x8* src = (const f16x8*)(Yh + base);

    for (int i = t; i < 1024; i += 256) {
        int ch = i >> 7;
        int nn = i & 127;
        f16x8 v = src[ch * (ND / 8) + nq * 128 + nn];
        int c = g * 8 + ch;
        float ga = gamma[c], be = beta[c];
        float ob[8];
#pragma unroll
        for (int u = 0; u < 8; ++u) {
            float yn = ((float)v[u] - mean) * rstd * ga + be;
            float sg = 1.0f / (1.0f + __expf(-yn));
            ob[u] = yn * sg;
        }
        float* dp = out + base + (size_t)ch * ND + nq * 1024 + nn * 8;
        *(float4*)dp       = *(float4*)&ob[0];
        *(float4*)(dp + 4) = *(float4*)&ob[4];
    }
}

// ============================================================================
extern "C" void kernel_launch(void* const* d_in, const int* in_sizes, int n_in,
                              void* d_out, int out_size, void* d_ws, size_t ws_size,
                              hipStream_t stream)
{
    const float* x     = (const float*)d_in[0];
    const float* Wq    = (const float*)d_in[1];
    const float* bq    = (const float*)d_in[2];
    const float* Wk    = (const float*)d_in[3];
    const float* bk    = (const float*)d_in[4];
    const float* Wv    = (const float*)d_in[5];
    const float* bv    = (const float*)d_in[6];
    const float* Wo    = (const float*)d_in[7];
    const float* bo    = (const float*)d_in[8];
    const float* gamma = (const float*)d_in[9];
    const float* beta  = (const float*)d_in[10];

    char* ws = (char*)d_ws;
    f16* Qt = (f16*)(ws);                    //  0..4 MiB   [B][N][C]
    f16* Kt = (f16*)(ws + (4u << 20));       //  4..8 MiB   [B][N][C]
    f16* Vb = (f16*)(ws + (8u << 20));       //  8..12 MiB  [B][C][N]
    f16* Hb = (f16*)(ws + (12u << 20));      // 12..16 MiB  [B][C][N]
    f16* Op = (f16*)(ws + (16u << 20));      // 16.. MiB    [KSN][B][C][N] (KSN=8: exactly 32 MiB)
    f16* Yh = (f16*)(ws + (16u << 20));      // reuses Op region after combine

    const bool big = ws_size >= (50ull << 20);

    if (big) {
        constexpr int KSN = 8;
        float* ml   = (float*)(ws + (48u << 20));                 // [48.0, 48.5)  512 KB
        float* wq   = (float*)(ws + (48u << 20) + (512u << 10));  // [48.5, 48.75) 256 KB
        float* part = (float*)(ws + (48u << 20) + (768u << 10));  // [48.75, ..)   32 KB
        f16*   Wh   = (f16*)(ws + (49u << 20));                   // [49.0, 49.5)  512 KB
        k_prep<<<dim3(128), 256, 0, stream>>>(Wq, Wk, Wv, Wo, Wh);
        k_proj_qkv<<<dim3(64, 4, 2), 256, 0, stream>>>(x, Wh, bq, bk, bv, Qt, Kt, Vb);
        k_attn<KSN><<<dim3(32 * KSN * 2), 256, 0, stream>>>(Qt, Kt, Vb, Op, ml);
        k_ml<KSN><<<dim3((2 * ND) / 256), 256, 0, stream>>>(ml, wq);
        k_comb<KSN><<<dim3((2 * CD * ND / 8) / 256), 256, 0, stream>>>(Op, wq, Hb);
        k_proj_o<<<dim3(64, 4, 2), 256, 0, stream>>>(Hb, Wh, bo, x, Yh, part);
        k_gn_silu<<<dim3(GD, 2, 4), 256, 0, stream>>>(Yh, part, gamma, beta, (float*)d_out);
    } else {
        constexpr int KSN = 4;
        float* ml   = (float*)(ws + (32u << 20));                 // [32.0, 32.25) (KSN=4: 256 KB)
        float* wq   = (float*)(ws + (32u << 20) + (512u << 10));  // [32.5, 32.625)
        float* part = (float*)(ws + (32u << 20) + (768u << 10));  // [32.75, ..)
        f16*   Wh   = (f16*)(ws + (33u << 20));                   // [33.0, 33.5)
        k_prep<<<dim3(128), 256, 0, stream>>>(Wq, Wk, Wv, Wo, Wh);
        k_proj_qkv<<<dim3(64, 4, 2), 256, 0, stream>>>(x, Wh, bq, bk, bv, Qt, Kt, Vb);
        k_attn<KSN><<<dim3(32 * KSN * 2), 256, 0, stream>>>(Qt, Kt, Vb, Op, ml);
        k_ml<KSN><<<dim3((2 * ND) / 256), 256, 0, stream>>>(ml, wq);
        k_comb<KSN><<<dim3((2 * CD * ND / 8) / 256), 256, 0, stream>>>(Op, wq, Hb);
        k_proj_o<<<dim3(64, 4, 2), 256, 0, stream>>>(Hb, Wh, bo, x, Yh, part);
        k_gn_silu<<<dim3(GD, 2, 4), 256, 0, stream>>>(Yh, part, gamma, beta, (float*)d_out);
    }
}

// Round 15
// 101.289 us; speedup vs baseline: 1.1043x; 1.0097x over previous
//
#include <hip/hip_runtime.h>
#include <hip/hip_bf16.h>

typedef _Float16 f16;
typedef __attribute__((ext_vector_type(2))) __fp16 h16x2;   // cvt_pkrtz return type
typedef __attribute__((ext_vector_type(4))) _Float16 f16x4;
typedef __attribute__((ext_vector_type(8))) _Float16 f16x8;
typedef __attribute__((ext_vector_type(4))) float f32x4;
typedef __attribute__((ext_vector_type(16))) float f32x16;
typedef __attribute__((ext_vector_type(4))) unsigned int u32x4;

#define CD 256
#define ND 4096
#define GD 32
#define KVB 32          // keys per iteration

// async global->LDS, 16B per lane, lds dest must be wave-uniform base
__device__ __forceinline__ void gl_lds16(const f16* g, f16* l) {
    __builtin_amdgcn_global_load_lds(
        (const __attribute__((address_space(1))) unsigned int*)g,
        (__attribute__((address_space(3))) unsigned int*)l,
        16, 0, 0);
}

// ============================================================================
// Kernel 0: pre-convert W matrices to f16.  Wh = [Wq|Wk|Wv|Wo] f16, 512 KB.
// ============================================================================
__global__ __launch_bounds__(256)
void k_prep(const float* __restrict__ Wq, const float* __restrict__ Wk,
            const float* __restrict__ Wv, const float* __restrict__ Wo,
            f16* __restrict__ Wh)
{
    const float* Ws[4] = { Wq, Wk, Wv, Wo };
    int i = blockIdx.x * 256 + threadIdx.x;       // over 4*65536/8 = 32768
    int p = i >> 13;                              // 8192 f16x8 per matrix
    int e = (i & 8191) * 8;
    const float* s = Ws[p] + e;
    float4 v0 = *(const float4*)s;
    float4 v1 = *(const float4*)(s + 4);
    f16x8 h = { (f16)v0.x, (f16)v0.y, (f16)v0.z, (f16)v0.w,
                (f16)v1.x, (f16)v1.y, (f16)v1.z, (f16)v1.w };
    *(f16x8*)(Wh + p * 65536 + e) = h;
}

// ============================================================================
// Kernel 1: fused QKV projection, BK=64, A staged from pre-converted Wh.
// p[b,o,n] = sum_c W[o,c] x[b,c,n] + bias[o]
// Q,K written TRANSPOSED [b][n][c] f16; V natural [b][c][n] f16.
// ============================================================================
__global__ __launch_bounds__(256)
void k_proj_qkv(const float* __restrict__ x, const f16* __restrict__ Wh,
                const float* __restrict__ bq, const float* __restrict__ bk,
                const float* __restrict__ bv,
                f16* __restrict__ Qt, f16* __restrict__ Kt, f16* __restrict__ Vb)
{
    __shared__ f16 As[3][64][72];
    __shared__ f16 Bs[64][72];
    __shared__ f16 Ts[64][72];

    const int t  = threadIdx.x;
    const int n0 = blockIdx.x * 64;
    const int o0 = blockIdx.y * 64;
    const int bb = blockIdx.z;

    const float* bs[3] = { bq, bk, bv };

    const int w  = t >> 6;
    const int l  = t & 63;
    const int lr = l & 15;
    const int lg = l >> 4;
    const int wo = (w >> 1) * 32;
    const int wn = (w & 1) * 32;

    const int sl  = t & 63;
    const int kc8 = (t >> 6) * 16;    // 16-element k chunk base

    f32x4 acc[3][2][2] = {};

    for (int ck = 0; ck < CD; ck += 64) {
        __syncthreads();
#pragma unroll
        for (int p = 0; p < 3; ++p) {   // A: f16 vector copies, no cvt
            const f16* s = Wh + p * 65536 + (size_t)(o0 + sl) * CD + ck + kc8;
            *(f16x8*)&As[p][sl][kc8]     = *(const f16x8*)s;
            *(f16x8*)&As[p][sl][kc8 + 8] = *(const f16x8*)(s + 8);
        }
        {   // B: 16 strided f32 loads + cvt (coalesced across lanes)
            const float* s = x + ((size_t)bb * CD + ck + kc8) * ND + n0 + sl;
#pragma unroll
            for (int u = 0; u < 16; ++u)
                Bs[sl][kc8 + u] = (f16)s[(size_t)u * ND];
        }
        __syncthreads();
#pragma unroll
        for (int kk = 0; kk < 2; ++kk) {
            f16x8 b0 = *(const f16x8*)&Bs[wn + lr][kk * 32 + lg * 8];
            f16x8 b1 = *(const f16x8*)&Bs[wn + 16 + lr][kk * 32 + lg * 8];
#pragma unroll
            for (int p = 0; p < 3; ++p) {
                f16x8 a0 = *(const f16x8*)&As[p][wo + lr][kk * 32 + lg * 8];
                f16x8 a1 = *(const f16x8*)&As[p][wo + 16 + lr][kk * 32 + lg * 8];
                acc[p][0][0] = __builtin_amdgcn_mfma_f32_16x16x32_f16(a0, b0, acc[p][0][0], 0, 0, 0);
                acc[p][0][1] = __builtin_amdgcn_mfma_f32_16x16x32_f16(a0, b1, acc[p][0][1], 0, 0, 0);
                acc[p][1][0] = __builtin_amdgcn_mfma_f32_16x16x32_f16(a1, b0, acc[p][1][0], 0, 0, 0);
                acc[p][1][1] = __builtin_amdgcn_mfma_f32_16x16x32_f16(a1, b1, acc[p][1][1], 0, 0, 0);
            }
        }
    }

    // Q, K: transpose via Ts then coalesced [n][c] writes
#pragma unroll
    for (int p = 0; p < 2; ++p) {
        __syncthreads();
#pragma unroll
        for (int so = 0; so < 2; ++so)
#pragma unroll
            for (int r = 0; r < 4; ++r) {
                int orow  = wo + so * 16 + lg * 4 + r;
                float bv_ = bs[p][o0 + orow];
#pragma unroll
                for (int sn = 0; sn < 2; ++sn)
                    Ts[orow][wn + sn * 16 + lr] = (f16)(acc[p][so][sn][r] + bv_);
            }
        __syncthreads();
        f16* dst = (p == 0) ? Qt : Kt;
        int n  = t >> 2;
        int o8 = (t & 3) * 16;
        f16 tmp[16];
#pragma unroll
        for (int u = 0; u < 16; ++u) tmp[u] = Ts[o8 + u][n];
        f16* g = dst + ((size_t)bb * ND + n0 + n) * CD + o0 + o8;
        *(f16x8*)g       = *(f16x8*)&tmp[0];
        *(f16x8*)(g + 8) = *(f16x8*)&tmp[8];
    }
    // V: direct [c][n] writes
#pragma unroll
    for (int so = 0; so < 2; ++so)
#pragma unroll
        for (int r = 0; r < 4; ++r) {
            int orow  = wo + so * 16 + lg * 4 + r;
            float bv_ = bv[o0 + orow];
#pragma unroll
            for (int sn = 0; sn < 2; ++sn) {
                int ncol = wn + sn * 16 + lr;
                Vb[((size_t)bb * CD + o0 + orow) * ND + n0 + ncol] =
                    (f16)(acc[2][so][sn][r] + bv_);
            }
        }
}

// ============================================================================
// Kernel 2: flash attention, split-K (template KSN), 32x32x16 MFMA.
// (unchanged from round 13 — verified)
// ============================================================================
template<int KSN>
__global__ __launch_bounds__(256, 2)
void k_attn(const f16* __restrict__ Qt, const f16* __restrict__ Kt,
            const f16* __restrict__ Vb, f16* __restrict__ Op,
            float* __restrict__ ml)
{
    __shared__ f16 Ks[2][32 * 256];   // [buf][row][chunk16B ^ (row&7)]  2x16 KB
    __shared__ f16 Vs[2][256 * 32];   // [buf][c][chunk16B ^ ((c>>1)&3)] 2x16 KB

    const int t   = threadIdx.x;
    const int w   = t >> 6;          // 0..3
    const int l   = t & 63;
    const int q32 = l & 31;          // this lane's query column / K row
    const int hi  = l >> 5;          // 0/1 half

    // ---- XCD-pinned decode ----
    const int bid = blockIdx.x;
    int bb, ks, qi;
    if constexpr (KSN == 8) {
        int xcd = bid & 7;
        bb = xcd & 1;
        ks = (xcd >> 1) | ((bid >> 8) << 2);
        qi = (bid >> 3) & 31;
    } else {   // KSN == 4
        bb = bid & 1;
        ks = (bid >> 1) & 3;
        qi = bid >> 3;
    }
    const int q0 = qi * 128 + w * 32;

    // K-row swizzle constants (row = q32): chunk (2n+hi)^s3 = 2*(n^t2) + hp
    const int s3 = q32 & 7;
    const int t2 = s3 >> 1;
    const int hp = hi ^ (s3 & 1);
    const int kb2 = q32 * 256 + hp * 8;     // per-lane K LDS base (elements)

    // Q fragments: qf[n] = logical chunk 2n+hi (channels n*16+hi*8 .. +7)
    f16x8 qf[16];
#pragma unroll
    for (int n = 0; n < 16; ++n)
        qf[n] = *(const f16x8*)(Qt + ((size_t)bb * ND + q0 + q32) * CD + n * 16 + hi * 8);

    // V per-lane constants
    const int sw  = (q32 >> 1) & 3;
    const int vb0 = q32 * 32 + (hi ^ sw) * 8;
    const int vb1 = q32 * 32 + ((2 + hi) ^ sw) * 8;

    f32x16 oacc[8] = {};      // 8 c-chunks of 32 rows; col=q32
    float row_m = -3.0e38f, row_l = 0.f;

    const int kv0 = ks * (ND / KSN);
    const f16* ktb = Kt + (size_t)bb * ND * CD;
    const f16* vbb = Vb + (size_t)bb * CD * ND;

    // per-lane loop-invariant staging offsets (elements)
    int koff[4], voff[4];
#pragma unroll
    for (int j = 0; j < 4; ++j) {
        int v   = (w * 4 + j) * 64 + l;
        int row = v >> 5;
        int ch  = (v & 31) ^ (row & 7);
        koff[j] = row * CD + ch * 8;
        int c   = v >> 2;
        int u   = (v & 3) ^ ((c >> 1) & 3);
        voff[j] = c * ND + u * 8;
    }

    auto stage = [&](int m0, int bi) {
#pragma unroll
        for (int j = 0; j < 4; ++j)
            gl_lds16(ktb + (size_t)m0 * CD + koff[j], &Ks[bi][(w * 4 + j) * 512]);
#pragma unroll
        for (int j = 0; j < 4; ++j)
            gl_lds16(vbb + m0 + voff[j], &Vs[bi][(w * 4 + j) * 512]);
    };

    stage(kv0, 0);
    __syncthreads();    // drains vmcnt; tile 0 resident

    const int NIT = (ND / KSN) / KVB;
    for (int it = 0; it < NIT; ++it) {
        const int bi = it & 1;
        if (it + 1 < NIT) stage(kv0 + (it + 1) * KVB, bi ^ 1);

        // ---- QK^T: per-lane swizzled K addresses (kb2 + (n^t2)*16) ----
        f32x16 sa = {}, sb = {};
        __builtin_amdgcn_s_setprio(1);
#pragma unroll
        for (int n = 0; n < 16; n += 2) {
            f16x8 ka = *(const f16x8*)&Ks[bi][kb2 + ((n ^ t2) << 4)];
            f16x8 kb = *(const f16x8*)&Ks[bi][kb2 + (((n + 1) ^ t2) << 4)];
            sa = __builtin_amdgcn_mfma_f32_32x32x16_f16(ka, qf[n],     sa, 0, 0, 0);
            sb = __builtin_amdgcn_mfma_f32_32x32x16_f16(kb, qf[n + 1], sb, 0, 0, 0);
        }
        __builtin_amdgcn_s_setprio(0);

        // ---- lane-local online softmax (defer-max THR=5) ----
        float p[16];
#pragma unroll
        for (int r = 0; r < 16; ++r) p[r] = sa[r] + sb[r];
        float pm = p[0];
#pragma unroll
        for (int r = 1; r < 16; ++r) pm = fmaxf(pm, p[r]);
        pm = fmaxf(pm, __shfl_xor(pm, 32));
        bool need = (pm > row_m + 5.0f);
        float nm  = need ? pm : row_m;
#pragma unroll
        for (int r = 0; r < 16; ++r) p[r] = __expf(p[r] - nm);
        float ps = 0.f;
#pragma unroll
        for (int r = 0; r < 16; ++r) ps += p[r];
        ps += __shfl_xor(ps, 32);
        if (__any(need)) {
            float sc = __expf(row_m - nm);   // == 1 for lanes w/o change
            row_l = row_l * sc + ps;
#pragma unroll
            for (int cc = 0; cc < 8; ++cc)
#pragma unroll
                for (int r = 0; r < 16; ++r) oacc[cc][r] *= sc;
        } else {
            row_l += ps;
        }
        row_m = nm;

        // ---- P -> PV B-operand via cvt_pkrtz + permlane32_swap ----
        unsigned int wv[8];
#pragma unroll
        for (int c = 0; c < 4; ++c) {
            h16x2 a = __builtin_amdgcn_cvt_pkrtz(p[4 * c],     p[4 * c + 1]);
            h16x2 b = __builtin_amdgcn_cvt_pkrtz(p[4 * c + 2], p[4 * c + 3]);
            wv[2 * c]     = __builtin_bit_cast(unsigned int, a);
            wv[2 * c + 1] = __builtin_bit_cast(unsigned int, b);
        }
        f16x8 pb[2];
#pragma unroll
        for (int j = 0; j < 2; ++j) {
            unsigned int a0 = wv[4 * j],     c0 = wv[4 * j + 2];
            unsigned int a1 = wv[4 * j + 1], c1 = wv[4 * j + 3];
            asm volatile("v_permlane32_swap_b32 %0, %1" : "+v"(a0), "+v"(c0));
            asm volatile("v_permlane32_swap_b32 %0, %1" : "+v"(a1), "+v"(c1));
            u32x4 bw = { a0, a1, c0, c1 };
            pb[j] = __builtin_bit_cast(f16x8, bw);
        }

        // ---- PV: O[c][q] += V[c][m] * P[m][q], 8 c-chunks x 2 m-halves ----
        __builtin_amdgcn_s_setprio(1);
#pragma unroll
        for (int cc = 0; cc < 8; ++cc) {
            f16x8 v0 = *(const f16x8*)&Vs[bi][cc * 1024 + vb0];
            f16x8 v1 = *(const f16x8*)&Vs[bi][cc * 1024 + vb1];
            oacc[cc] = __builtin_amdgcn_mfma_f32_32x32x16_f16(v0, pb[0], oacc[cc], 0, 0, 0);
            oacc[cc] = __builtin_amdgcn_mfma_f32_32x32x16_f16(v1, pb[1], oacc[cc], 0, 0, 0);
        }
        __builtin_amdgcn_s_setprio(0);
        __syncthreads();   // drains stage(it+1); frees buffers for next iter
    }

    // ---- write unnormalized partial + (m,l) ----
#pragma unroll
    for (int cc = 0; cc < 8; ++cc)
#pragma unroll
        for (int r = 0; r < 16; ++r) {
            int cch = cc * 32 + (r & 3) + 8 * (r >> 2) + 4 * hi;
            Op[(((size_t)ks * 2 + bb) * CD + cch) * ND + q0 + q32] = (f16)oacc[cc][r];
        }
    if (l < 32) {
        int n = q0 + l;
        ml[((ks * 2 + bb) * 2 + 0) * ND + n] = row_m;
        ml[((ks * 2 + bb) * 2 + 1) * ND + n] = row_l;
    }
}

// ============================================================================
// Kernel 2b-i: per-n combine weights  wq[ks][b][n] = exp(m-M)/L
// ============================================================================
template<int KSN>
__global__ __launch_bounds__(256)
void k_ml(const float* __restrict__ ml, float* __restrict__ wq)
{
    int i = blockIdx.x * 256 + threadIdx.x;   // i over B*ND
    int b = i / ND, n = i % ND;
    float m[KSN], lv[KSN];
#pragma unroll
    for (int ks = 0; ks < KSN; ++ks) {
        m[ks]  = ml[((ks * 2 + b) * 2 + 0) * ND + n];
        lv[ks] = ml[((ks * 2 + b) * 2 + 1) * ND + n];
    }
    float M = m[0];
#pragma unroll
    for (int ks = 1; ks < KSN; ++ks) M = fmaxf(M, m[ks]);
    float wgt[KSN], L = 0.f;
#pragma unroll
    for (int ks = 0; ks < KSN; ++ks) { wgt[ks] = __expf(m[ks] - M); L += wgt[ks] * lv[ks]; }
    float inv = 1.0f / L;
#pragma unroll
    for (int ks = 0; ks < KSN; ++ks)
        wq[(ks * 2 + b) * ND + n] = wgt[ks] * inv;
}

// ============================================================================
// Kernel 2b-ii: combine split-K partials -> Hb[b][c][n] f16 (vectorized)
// ============================================================================
template<int KSN>
__global__ __launch_bounds__(256)
void k_comb(const f16* __restrict__ Op, const float* __restrict__ wq,
            f16* __restrict__ Hb)
{
    size_t i = (size_t)blockIdx.x * 256 + threadIdx.x;   // one f16x8 each
    int n0 = (int)(i % (ND / 8)) * 8;
    int c  = (int)((i / (ND / 8)) % CD);
    int b  = (int)(i / ((size_t)CD * (ND / 8)));

    float acc[8] = {};
#pragma unroll
    for (int ks = 0; ks < KSN; ++ks) {
        f16x8 o = *(const f16x8*)(Op + (((size_t)ks * 2 + b) * CD + c) * ND + n0);
        const float* wp = wq + (ks * 2 + b) * ND + n0;
        float4 w0 = *(const float4*)wp;
        float4 w1 = *(const float4*)(wp + 4);
        acc[0] += w0.x * (float)o[0]; acc[1] += w0.y * (float)o[1];
        acc[2] += w0.z * (float)o[2]; acc[3] += w0.w * (float)o[3];
        acc[4] += w1.x * (float)o[4]; acc[5] += w1.y * (float)o[5];
        acc[6] += w1.z * (float)o[6]; acc[7] += w1.w * (float)o[7];
    }
    f16x8 h;
#pragma unroll
    for (int u = 0; u < 8; ++u) h[u] = (f16)acc[u];
    *(f16x8*)(Hb + ((size_t)b * CD + c) * ND + n0) = h;
}

// ============================================================================
// Kernel 3: output projection + residual, BK=64, A from Wh[3].
// Yh = f16(Wo@H + bo + x); emits deterministic GroupNorm partials.
// ============================================================================
__global__ __launch_bounds__(256)
void k_proj_o(const f16* __restrict__ Hb, const f16* __restrict__ Wh,
              const float* __restrict__ bo, const float* __restrict__ x,
              f16* __restrict__ Yh, float* __restrict__ part)
{
    __shared__ f16 As[64][72];
    __shared__ f16 Bs[64][72];
    __shared__ float rs[4][2][2][2];   // [wave][so][lg>>1][{s,s2}]

    const int t  = threadIdx.x;
    const int n0 = blockIdx.x * 64;
    const int o0 = blockIdx.y * 64;
    const int bb = blockIdx.z;

    const int w  = t >> 6;
    const int l  = t & 63;
    const int lr = l & 15;
    const int lg = l >> 4;
    const int wo = (w >> 1) * 32;
    const int wn = (w & 1) * 32;

    const int sl  = t & 63;
    const int kc8 = (t >> 6) * 16;

    const f16* Wo16 = Wh + 3 * 65536;

    f32x4 acc[2][2] = {};

    for (int ck = 0; ck < CD; ck += 64) {
        __syncthreads();
        {
            const f16* s = Wo16 + (size_t)(o0 + sl) * CD + ck + kc8;
            *(f16x8*)&As[sl][kc8]     = *(const f16x8*)s;
            *(f16x8*)&As[sl][kc8 + 8] = *(const f16x8*)(s + 8);
        }
        {
            const f16* s = Hb + ((size_t)bb * CD + ck + kc8) * ND + n0 + sl;
#pragma unroll
            for (int u = 0; u < 16; ++u)
                Bs[sl][kc8 + u] = s[(size_t)u * ND];
        }
        __syncthreads();
#pragma unroll
        for (int kk = 0; kk < 2; ++kk) {
            f16x8 a0 = *(const f16x8*)&As[wo + lr][kk * 32 + lg * 8];
            f16x8 a1 = *(const f16x8*)&As[wo + 16 + lr][kk * 32 + lg * 8];
            f16x8 b0 = *(const f16x8*)&Bs[wn + lr][kk * 32 + lg * 8];
            f16x8 b1 = *(const f16x8*)&Bs[wn + 16 + lr][kk * 32 + lg * 8];
            acc[0][0] = __builtin_amdgcn_mfma_f32_16x16x32_f16(a0, b0, acc[0][0], 0, 0, 0);
            acc[0][1] = __builtin_amdgcn_mfma_f32_16x16x32_f16(a0, b1, acc[0][1], 0, 0, 0);
            acc[1][0] = __builtin_amdgcn_mfma_f32_16x16x32_f16(a1, b0, acc[1][0], 0, 0, 0);
            acc[1][1] = __builtin_amdgcn_mfma_f32_16x16x32_f16(a1, b1, acc[1][1], 0, 0, 0);
        }
    }

#pragma unroll
    for (int so = 0; so < 2; ++so) {
        float ls = 0.f, ls2 = 0.f;
#pragma unroll
        for (int r = 0; r < 4; ++r) {
            int orow  = wo + so * 16 + lg * 4 + r;
            float bv_ = bo[o0 + orow];
#pragma unroll
            for (int sn = 0; sn < 2; ++sn) {
                int ncol   = wn + sn * 16 + lr;
                size_t idx = ((size_t)bb * CD + o0 + orow) * ND + n0 + ncol;
                float v = acc[so][sn][r] + bv_ + x[idx];
                Yh[idx] = (f16)v;
                ls  += v;
                ls2 += v * v;
            }
        }
        // deterministic reduce over lanes sharing the same group
#pragma unroll
        for (int m = 1; m <= 16; m <<= 1) {
            ls  += __shfl_xor(ls, m);
            ls2 += __shfl_xor(ls2, m);
        }
        if ((l & 31) == 0) {
            rs[w][so][l >> 5][0] = ls;
            rs[w][so][l >> 5][1] = ls2;
        }
    }
    __syncthreads();
    if (t < 16) {
        int gl = t >> 1, st = t & 1;
        int a = gl >> 2, so = (gl >> 1) & 1, lh = gl & 1;
        float v = rs[2 * a][so][lh][st] + rs[2 * a + 1][so][lh][st];
        part[(((size_t)bb * GD + (o0 >> 3) + gl) * 64 + blockIdx.x) * 2 + st] = v;
    }
}

// ============================================================================
// Kernel 4: GroupNorm (from partials) + SiLU, single pass, f16 in / f32 out
// grid (32 groups, 2 batch, 8 n-eighths) = 512 blocks = 2/CU
// ============================================================================
__global__ __launch_bounds__(256)
void k_gn_silu(const f16* __restrict__ Yh, const float* __restrict__ part,
               const float* __restrict__ gamma, const float* __restrict__ beta,
               float* __restrict__ out)
{
    const int g  = blockIdx.x, b = blockIdx.y, nq = blockIdx.z;
    const int t  = threadIdx.x;

    __shared__ float mr[2];
    if (t < 64) {
        float s  = part[(((size_t)b * GD + g) * 64 + t) * 2 + 0];
        float s2 = part[(((size_t)b * GD + g) * 64 + t) * 2 + 1];
#pragma unroll
        for (int m = 1; m < 64; m <<= 1) {
            s  += __shfl_xor(s, m);
            s2 += __shfl_xor(s2, m);
        }
        if (t == 0) {
            float mean = s / 32768.f;
            float var  = s2 / 32768.f - mean * mean;
            mr[0] = mean;
            mr[1] = rsqrtf(var + 1e-5f);
        }
    }
    __syncthreads();
    const float mean = mr[0], rstd = mr[1];

    const size_t base = ((size_t)b * CD + g * 8) * ND;
    const f16x8* src = (const f16x8*)(Yh + base);

    // 8 channels x 512 n per block = 512 f16x8
    for (int i = t; i < 512; i += 256) {
        int ch = i >> 6;                 // 64 f16x8 per channel-eighth
        int nn = i & 63;
        f16x8 v = src[ch * (ND / 8) + nq * 64 + nn];
        int c = g * 8 + ch;
        float ga = gamma[c], be = beta[c];
        float ob[8];
#pragma unroll
        for (int u = 0; u < 8; ++u) {
            float yn = ((float)v[u] - mean) * rstd * ga + be;
            float sg = 1.0f / (1.0f + __expf(-yn));
            ob[u] = yn * sg;
        }
        float* dp = out + base + (size_t)ch * ND + nq * 512 + nn * 8;
        *(float4*)dp       = *(float4*)&ob[0];
        *(float4*)(dp + 4) = *(float4*)&ob[4];
    }
}

// ============================================================================
extern "C" void kernel_launch(void* const* d_in, const int* in_sizes, int n_in,
                              void* d_out, int out_size, void* d_ws, size_t ws_size,
                              hipStream_t stream)
{
    const float* x     = (const float*)d_in[0];
    const float* Wq    = (const float*)d_in[1];
    const float* bq    = (const float*)d_in[2];
    const float* Wk    = (const float*)d_in[3];
    const float* bk    = (const float*)d_in[4];
    const float* Wv    = (const float*)d_in[5];
    const float* bv    = (const float*)d_in[6];
    const float* Wo    = (const float*)d_in[7];
    const float* bo    = (const float*)d_in[8];
    const float* gamma = (const float*)d_in[9];
    const float* beta  = (const float*)d_in[10];

    char* ws = (char*)d_ws;
    f16* Qt = (f16*)(ws);                    //  0..4 MiB   [B][N][C]
    f16* Kt = (f16*)(ws + (4u << 20));       //  4..8 MiB   [B][N][C]
    f16* Vb = (f16*)(ws + (8u << 20));       //  8..12 MiB  [B][C][N]
    f16* Hb = (f16*)(ws + (12u << 20));      // 12..16 MiB  [B][C][N]
    f16* Op = (f16*)(ws + (16u << 20));      // 16.. MiB    [KSN][B][C][N] (KSN=8: exactly 32 MiB)
    f16* Yh = (f16*)(ws + (16u << 20));      // reuses Op region after combine

    const bool big = ws_size >= (50ull << 20);

    if (big) {
        constexpr int KSN = 8;
        float* ml   = (float*)(ws + (48u << 20));                 // [48.0, 48.5)  512 KB
        float* wq   = (float*)(ws + (48u << 20) + (512u << 10));  // [48.5, 48.75) 256 KB
        float* part = (float*)(ws + (48u << 20) + (768u << 10));  // [48.75, ..)   32 KB
        f16*   Wh   = (f16*)(ws + (49u << 20));                   // [49.0, 49.5)  512 KB
        k_prep<<<dim3(128), 256, 0, stream>>>(Wq, Wk, Wv, Wo, Wh);
        k_proj_qkv<<<dim3(64, 4, 2), 256, 0, stream>>>(x, Wh, bq, bk, bv, Qt, Kt, Vb);
        k_attn<KSN><<<dim3(32 * KSN * 2), 256, 0, stream>>>(Qt, Kt, Vb, Op, ml);
        k_ml<KSN><<<dim3((2 * ND) / 256), 256, 0, stream>>>(ml, wq);
        k_comb<KSN><<<dim3((2 * CD * ND / 8) / 256), 256, 0, stream>>>(Op, wq, Hb);
        k_proj_o<<<dim3(64, 4, 2), 256, 0, stream>>>(Hb, Wh, bo, x, Yh, part);
        k_gn_silu<<<dim3(GD, 2, 8), 256, 0, stream>>>(Yh, part, gamma, beta, (float*)d_out);
    } else {
        constexpr int KSN = 4;
        float* ml   = (float*)(ws + (32u << 20));                 // [32.0, 32.25)
        float* wq   = (float*)(ws + (32u << 20) + (512u << 10));  // [32.5, 32.625)
        float* part = (float*)(ws + (32u << 20) + (768u << 10));  // [32.75, ..)
        f16*   Wh   = (f16*)(ws + (33u << 20));                   // [33.0, 33.5)
        k_prep<<<dim3(128), 256, 0, stream>>>(Wq, Wk, Wv, Wo, Wh);
        k_proj_qkv<<<dim3(64, 4, 2), 256, 0, stream>>>(x, Wh, bq, bk, bv, Qt, Kt, Vb);
        k_attn<KSN><<<dim3(32 * KSN * 2), 256, 0, stream>>>(Qt, Kt, Vb, Op, ml);
        k_ml<KSN><<<dim3((2 * ND) / 256), 256, 0, stream>>>(ml, wq);
        k_comb<KSN><<<dim3((2 * CD * ND / 8) / 256), 256, 0, stream>>>(Op, wq, Hb);
        k_proj_o<<<dim3(64, 4, 2), 256, 0, stream>>>(Hb, Wh, bo, x, Yh, part);
        k_gn_silu<<<dim3(GD, 2, 8), 256, 0, stream>>>(Yh, part, gamma, beta, (float*)d_out);
    }
}